// Round 1
// baseline (6505.370 us; speedup 1.0000x reference)
//
#include <hip/hip_runtime.h>
#include <math.h>

#define NN   16384
#define EE   262144

// ---------------- init (zero barrier/deg/fill) ----------------
__global__ void k_init(int* __restrict__ bar, int* __restrict__ deg, int* __restrict__ fill) {
    int i = blockIdx.x * 256 + threadIdx.x;
    if (i < 128 * 32) bar[i] = 0;
    if (i < NN) { deg[i] = 0; fill[i] = 0; }
}

// ---------------- embedding gather ----------------
__global__ void k_embed(const int* __restrict__ wseq, const float* __restrict__ tab,
                        float* __restrict__ xe) {
    int i = blockIdx.x * 256 + threadIdx.x;
    if (i >= NN * 75) return;              // 300 floats = 75 float4 per row
    int row = i / 75;
    int c = i - row * 75;
    int wid = wseq[row];
    ((float4*)xe)[row * 75 + c] = ((const float4*)tab)[wid * 75 + c];
}

// ---------------- GEMM: C[M][N] = A[M][K] * B + bias ----------------
// TRANSB=1: B1 is (N,K) row-major (B2 unused).
// TRANSB=0: row r<K1 from B1[(K1,N)], else B2[(K-K1,N)].
template<int TRANSB>
__global__ __launch_bounds__(256)
void k_gemm(const float* __restrict__ A, const float* __restrict__ B1,
            const float* __restrict__ B2, const float* __restrict__ bias,
            float* __restrict__ C, int M, int N, int K, int K1)
{
    __shared__ float As[8][132];
    __shared__ float Bs[8][132];
    const int tid = threadIdx.x;
    const int mb = M >> 7;
    const int bm = blockIdx.x % mb;
    const int bn = blockIdx.x / mb;
    const int m0 = bm << 7, n0 = bn << 7;
    const int tx = tid & 15, ty = tid >> 4;

    float acc[8][8];
    #pragma unroll
    for (int i = 0; i < 8; ++i)
        #pragma unroll
        for (int j = 0; j < 8; ++j) acc[i][j] = 0.f;

    for (int k0 = 0; k0 < K; k0 += 8) {
        {   // stage A -> As[k][m]
            int m = tid >> 1, q = (tid & 1) * 4;
            const float* ap = A + (m0 + m) * K + k0 + q;
            float4 v;
            if (k0 + q + 3 < K) v = *(const float4*)ap;
            else {
                v.x = (k0+q+0 < K) ? ap[0] : 0.f;
                v.y = (k0+q+1 < K) ? ap[1] : 0.f;
                v.z = (k0+q+2 < K) ? ap[2] : 0.f;
                v.w = (k0+q+3 < K) ? ap[3] : 0.f;
            }
            As[q+0][m] = v.x; As[q+1][m] = v.y; As[q+2][m] = v.z; As[q+3][m] = v.w;
        }
        if (TRANSB) {   // B1 (N,K): Bs[k][n] = B1[n][k]
            int n = tid >> 1, q = (tid & 1) * 4;
            const float* bp = B1 + (n0 + n) * K + k0 + q;
            float4 v;
            if (k0 + q + 3 < K) v = *(const float4*)bp;
            else {
                v.x = (k0+q+0 < K) ? bp[0] : 0.f;
                v.y = (k0+q+1 < K) ? bp[1] : 0.f;
                v.z = (k0+q+2 < K) ? bp[2] : 0.f;
                v.w = (k0+q+3 < K) ? bp[3] : 0.f;
            }
            Bs[q+0][n] = v.x; Bs[q+1][n] = v.y; Bs[q+2][n] = v.z; Bs[q+3][n] = v.w;
        } else {        // B (K,N) split across B1/B2
            int kk = tid >> 5, nq = (tid & 31) * 4;
            int r = k0 + kk;
            const float* bp = (r < K1) ? (B1 + r * N + n0 + nq)
                                       : (B2 + (r - K1) * N + n0 + nq);
            *(float4*)&Bs[kk][nq] = *(const float4*)bp;
        }
        __syncthreads();
        #pragma unroll
        for (int kk = 0; kk < 8; ++kk) {
            float a[8], b[8];
            *(float4*)&a[0] = *(const float4*)&As[kk][ty*8];
            *(float4*)&a[4] = *(const float4*)&As[kk][ty*8+4];
            *(float4*)&b[0] = *(const float4*)&Bs[kk][tx*8];
            *(float4*)&b[4] = *(const float4*)&Bs[kk][tx*8+4];
            #pragma unroll
            for (int i = 0; i < 8; ++i)
                #pragma unroll
                for (int j = 0; j < 8; ++j)
                    acc[i][j] += a[i] * b[j];
        }
        __syncthreads();
    }
    #pragma unroll
    for (int i = 0; i < 8; ++i) {
        int m = m0 + ty*8 + i;
        float* cp = C + m * N + n0 + tx*8;
        #pragma unroll
        for (int j = 0; j < 8; j += 4) {
            float4 v;
            v.x = acc[i][j+0] + bias[n0 + tx*8 + j+0];
            v.y = acc[i][j+1] + bias[n0 + tx*8 + j+1];
            v.z = acc[i][j+2] + bias[n0 + tx*8 + j+2];
            v.w = acc[i][j+3] + bias[n0 + tx*8 + j+3];
            *(float4*)(cp + j) = v;
        }
    }
}

// ---------------- LSTM recurrence (both directions) ----------------
// grid = 256 wgs: wid = gs*32 + (dir*16 + bs). Group (dir,bs) = 8 wgs
// (all gs) is the complete producer/consumer set for h rows b0..b0+7,
// so only that group barriers each step. whh slice lives in VGPRs
// (128/thread), 8-way K split, partials reduced through LDS.
__global__ __launch_bounds__(256, 1)
void k_lstm(const float* __restrict__ xs_f, const float* __restrict__ xs_b,
            const float* __restrict__ whh_f, const float* __restrict__ whh_b,
            float* __restrict__ xout, float* __restrict__ hbuf,
            int* __restrict__ bar)
{
    const int tid = threadIdx.x;
    const int wid = blockIdx.x;
    const int grp = wid & 31;       // dir*16 + bs
    const int gs  = wid >> 5;       // 0..7
    const int dir = grp >> 4;
    const int bs  = grp & 15;
    const int j0 = gs * 32, b0 = bs * 8;
    const float* xs  = dir ? xs_b : xs_f;
    const float* whh = dir ? whh_b : whh_f;
    float* hb = hbuf + dir * (2 * 128 * 256);

    // compute role: ri -> 4 gate-rows, kq -> 32-wide k slice
    const int ri = tid & 31, kq = tid >> 5;
    float wreg[4][32];
    #pragma unroll
    for (int rr = 0; rr < 4; ++rr) {
        int r = 4 * ri + rr;
        int g = r >> 5, jj = r & 31;
        const float* wrow = whh + (g * 256 + j0 + jj) * 256 + kq * 32;
        #pragma unroll
        for (int kk = 0; kk < 32; ++kk) wreg[rr][kk] = wrow[kk];
    }
    // update role: one (hidden j, batch b) cell per thread
    const int jj_u = tid & 31, bb_u = tid >> 5;
    float c_reg = 0.f;

    __shared__ float Hs[8][260];
    __shared__ float ps[8][128][9];

    for (int t = 0; t < 128; ++t) {
        const int l = dir ? (127 - t) : t;
        const int n_u = (b0 + bb_u) * 128 + l;
        const float* xr = xs + n_u * 1024 + j0 + jj_u;
        float xi = xr[0], xf = xr[256], xg = xr[512], xo = xr[768];

        if (t > 0) {
            const float* hsrc = hb + (t & 1) * (128 * 256);
            {   // stage h slice (8 rows x 256) into LDS
                int b = tid >> 5, ks = (tid & 31) * 8;
                const float* hp = hsrc + (b0 + b) * 256 + ks;
                float4 v0 = *(const float4*)hp;
                float4 v1 = *(const float4*)(hp + 4);
                *(float4*)&Hs[b][ks]     = v0;
                *(float4*)&Hs[b][ks + 4] = v1;
            }
            __syncthreads();
            float accp[4][8];
            #pragma unroll
            for (int rr = 0; rr < 4; ++rr)
                #pragma unroll
                for (int bb = 0; bb < 8; ++bb) accp[rr][bb] = 0.f;
            #pragma unroll
            for (int k4 = 0; k4 < 8; ++k4) {
                #pragma unroll
                for (int bb = 0; bb < 8; ++bb) {
                    float4 h4 = *(const float4*)&Hs[bb][kq * 32 + k4 * 4];
                    #pragma unroll
                    for (int rr = 0; rr < 4; ++rr) {
                        accp[rr][bb] += wreg[rr][k4*4+0] * h4.x
                                      + wreg[rr][k4*4+1] * h4.y
                                      + wreg[rr][k4*4+2] * h4.z
                                      + wreg[rr][k4*4+3] * h4.w;
                    }
                }
            }
            #pragma unroll
            for (int rr = 0; rr < 4; ++rr) {
                int r = 4 * ri + rr;
                #pragma unroll
                for (int bb = 0; bb < 8; ++bb) ps[kq][r][bb] = accp[rr][bb];
            }
        }
        __syncthreads();

        float gi = xi, gf = xf, gg = xg, go = xo;
        if (t > 0) {
            #pragma unroll
            for (int q = 0; q < 8; ++q) {
                gi += ps[q][     jj_u][bb_u];
                gf += ps[q][32 + jj_u][bb_u];
                gg += ps[q][64 + jj_u][bb_u];
                go += ps[q][96 + jj_u][bb_u];
            }
        }
        gi = 1.f / (1.f + expf(-gi));
        gf = 1.f / (1.f + expf(-gf));
        gg = tanhf(gg);
        go = 1.f / (1.f + expf(-go));
        c_reg = gf * c_reg + gi * gg;
        float h = go * tanhf(c_reg);

        xout[n_u * 512 + dir * 256 + j0 + jj_u] = h;
        hb[((t + 1) & 1) * (128 * 256) + (b0 + bb_u) * 256 + j0 + jj_u] = h;

        if (t < 127) {
            __threadfence();          // release h stores to device scope
            __syncthreads();
            if (tid == 0) {
                int* bp = bar + t * 32 + grp;
                atomicAdd(bp, 1);
                while (__hip_atomic_load(bp, __ATOMIC_RELAXED, __HIP_MEMORY_SCOPE_AGENT) < 8)
                    __builtin_amdgcn_s_sleep(2);
            }
            __syncthreads();
            __threadfence();          // acquire: invalidate L1/L2 before reading fresh h
        }
    }
}

// ---------------- CSR build ----------------
__global__ void k_hist(const int* __restrict__ ei, int* __restrict__ deg) {
    int e = blockIdx.x * 256 + threadIdx.x;
    if (e >= EE) return;
    atomicAdd(&deg[ei[EE + e]], 1);
}

__global__ void k_scan(const int* __restrict__ deg, int* __restrict__ indptr) {
    __shared__ int sm[256];
    int tid = threadIdx.x;
    int b0 = tid * 64;
    int s = 0;
    for (int i = 0; i < 64; ++i) s += deg[b0 + i];
    sm[tid] = s;
    __syncthreads();
    for (int off = 1; off < 256; off <<= 1) {
        int v = (tid >= off) ? sm[tid - off] : 0;
        __syncthreads();
        sm[tid] += v;
        __syncthreads();
    }
    int run = sm[tid] - s;   // exclusive prefix
    for (int i = 0; i < 64; ++i) { indptr[b0 + i] = run; run += deg[b0 + i]; }
    if (tid == 255) indptr[NN] = run;
}

__global__ void k_scatter(const int* __restrict__ ei, const int* __restrict__ indptr,
                          int* __restrict__ fill, int* __restrict__ cols) {
    int e = blockIdx.x * 256 + threadIdx.x;
    if (e >= EE) return;
    int d = ei[EE + e];
    int slot = atomicAdd(&fill[d], 1);
    cols[indptr[d] + slot] = ei[e];
}

// ---------------- SAGE neighbor mean + concat ----------------
// one wave per dst node; cat[n] = [agg(n) (512) | x(n) (512)]
__global__ __launch_bounds__(256)
void k_gather(const float* __restrict__ x, const int* __restrict__ indptr,
              const int* __restrict__ cols, float* __restrict__ cat)
{
    int gw = (blockIdx.x * 256 + threadIdx.x) >> 6;
    int lane = threadIdx.x & 63;
    if (gw >= NN) return;
    int s = indptr[gw], e = indptr[gw + 1];
    float a0=0,a1=0,a2=0,a3=0,a4=0,a5=0,a6=0,a7=0;
    for (int p = s; p < e; ++p) {
        const float4* xp = (const float4*)(x + cols[p] * 512 + lane * 8);
        float4 v0 = xp[0], v1 = xp[1];
        a0 += v0.x; a1 += v0.y; a2 += v0.z; a3 += v0.w;
        a4 += v1.x; a5 += v1.y; a6 += v1.z; a7 += v1.w;
    }
    float sc = 1.f / (float)((e - s) > 1 ? (e - s) : 1);
    float* cp = cat + gw * 1024 + lane * 8;
    float4 o0 = { a0*sc, a1*sc, a2*sc, a3*sc };
    float4 o1 = { a4*sc, a5*sc, a6*sc, a7*sc };
    *(float4*)cp = o0;
    *(float4*)(cp + 4) = o1;
    const float4* xp = (const float4*)(x + gw * 512 + lane * 8);
    *(float4*)(cp + 512) = xp[0];
    *(float4*)(cp + 516) = xp[1];
}

// ---------------- row L2-normalize + relu (in place) ----------------
__global__ __launch_bounds__(256)
void k_norm_relu(float* __restrict__ y)
{
    int gw = (blockIdx.x * 256 + threadIdx.x) >> 6;
    int lane = threadIdx.x & 63;
    if (gw >= NN) return;
    float* row = y + gw * 512 + lane * 8;
    float4 v0 = *(const float4*)row;
    float4 v1 = *(const float4*)(row + 4);
    float ss = v0.x*v0.x + v0.y*v0.y + v0.z*v0.z + v0.w*v0.w
             + v1.x*v1.x + v1.y*v1.y + v1.z*v1.z + v1.w*v1.w;
    #pragma unroll
    for (int off = 32; off >= 1; off >>= 1) ss += __shfl_xor(ss, off);
    float sc = 1.f / fmaxf(sqrtf(ss), 1e-12f);
    float4 o0, o1;
    o0.x = fmaxf(v0.x*sc, 0.f); o0.y = fmaxf(v0.y*sc, 0.f);
    o0.z = fmaxf(v0.z*sc, 0.f); o0.w = fmaxf(v0.w*sc, 0.f);
    o1.x = fmaxf(v1.x*sc, 0.f); o1.y = fmaxf(v1.y*sc, 0.f);
    o1.z = fmaxf(v1.z*sc, 0.f); o1.w = fmaxf(v1.w*sc, 0.f);
    *(float4*)row = o0;
    *(float4*)(row + 4) = o1;
}

// ---------------- mean-pool per graph + linear head ----------------
__global__ __launch_bounds__(256)
void k_pool(const float* __restrict__ x, const float* __restrict__ Wlin,
            const float* __restrict__ blin, float* __restrict__ out)
{
    int g = blockIdx.x;
    int tid = threadIdx.x;
    const float* base = x + g * 128 * 512;
    float a0 = 0.f, a1 = 0.f;
    for (int r = 0; r < 128; ++r) {
        a0 += base[r * 512 + 2*tid];
        a1 += base[r * 512 + 2*tid + 1];
    }
    __shared__ float pooled[512];
    pooled[2*tid]     = a0 * (1.f / 128.f);
    pooled[2*tid + 1] = a1 * (1.f / 128.f);
    __syncthreads();
    if (tid < 64) {
        float p0 = 0.f, p1 = 0.f;
        for (int k = tid; k < 512; k += 64) {
            float pv = pooled[k];
            p0 += pv * Wlin[2*k];
            p1 += pv * Wlin[2*k + 1];
        }
        #pragma unroll
        for (int off = 32; off >= 1; off >>= 1) {
            p0 += __shfl_xor(p0, off);
            p1 += __shfl_xor(p1, off);
        }
        if (tid == 0) {
            out[2*g]     = p0 + blin[0];
            out[2*g + 1] = p1 + blin[1];
        }
    }
}

extern "C" void kernel_launch(void* const* d_in, const int* in_sizes, int n_in,
                              void* d_out, int out_size, void* d_ws, size_t ws_size,
                              hipStream_t stream)
{
    (void)in_sizes; (void)n_in; (void)out_size; (void)ws_size;
    const int*   word_seq = (const int*)  d_in[0];
    const int*   ei       = (const int*)  d_in[1];
    const float* tab      = (const float*)d_in[3];
    const float* wih_f    = (const float*)d_in[4];
    const float* whh_f    = (const float*)d_in[5];
    const float* b_f      = (const float*)d_in[6];
    const float* wih_b    = (const float*)d_in[7];
    const float* whh_b    = (const float*)d_in[8];
    const float* b_b      = (const float*)d_in[9];
    const float* Wl1      = (const float*)d_in[10];
    const float* Wr1      = (const float*)d_in[11];
    const float* b1       = (const float*)d_in[12];
    const float* Wl2      = (const float*)d_in[13];
    const float* Wr2      = (const float*)d_in[14];
    const float* b2       = (const float*)d_in[15];
    const float* Wl3      = (const float*)d_in[16];
    const float* Wr3      = (const float*)d_in[17];
    const float* b3       = (const float*)d_in[18];
    const float* Wlin     = (const float*)d_in[19];
    const float* blin     = (const float*)d_in[20];
    float* out = (float*)d_out;

    char* w = (char*)d_ws;
    // region 0 (reused): xe lives here until proj GEMMs finish, then CSR/barrier/hbuf
    float* xe     = (float*)(w);                    // 19,660,800 B
    int*   bar    = (int*)  (w);                    //     16,384 B
    int*   deg    = (int*)  (w + 16384);            //     65,536 B
    int*   indptr = (int*)  (w + 81920);            //     66,048 B
    int*   fill   = (int*)  (w + 147968);           //     65,536 B
    int*   cols   = (int*)  (w + 213504);           //  1,048,576 B
    float* hbuf   = (float*)(w + 1262080);          //  1,048,576 B
    float* xs_f   = (float*)(w + 19660800);         // 67,108,864 B
    float* xs_b   = (float*)(w + 86769664);         // 67,108,864 B
    float* x0     = (float*)(w + 153878528);        // 33,554,432 B  (end ~179 MB)
    float* cat    = xs_f;                           // reuse after LSTM
    float* x1     = xs_b;                           // reuse after LSTM
    float* x2     = (float*)((char*)xs_b + 33554432);

    // embedding + LSTM input projections (xe live)
    k_embed<<<4800, 256, 0, stream>>>(word_seq, tab, xe);
    k_gemm<1><<<1024, 256, 0, stream>>>(xe, wih_f, nullptr, b_f, xs_f, NN, 1024, 300, 300);
    k_gemm<1><<<1024, 256, 0, stream>>>(xe, wih_b, nullptr, b_b, xs_b, NN, 1024, 300, 300);

    // CSR build (overwrites xe region — xe dead now)
    k_init<<<64, 256, 0, stream>>>(bar, deg, fill);
    k_hist<<<1024, 256, 0, stream>>>(ei, deg);
    k_scan<<<1, 256, 0, stream>>>(deg, indptr);
    k_scatter<<<1024, 256, 0, stream>>>(ei, indptr, fill, cols);

    // bidirectional LSTM scan -> x0 = [hf | hb]
    k_lstm<<<256, 256, 0, stream>>>(xs_f, xs_b, whh_f, whh_b, x0, hbuf, bar);

    // SAGE layer 1: x0 -> x1
    k_gather<<<4096, 256, 0, stream>>>(x0, indptr, cols, cat);
    k_gemm<0><<<512, 256, 0, stream>>>(cat, Wl1, Wr1, b1, x1, NN, 512, 1024, 512);
    k_norm_relu<<<4096, 256, 0, stream>>>(x1);
    // SAGE layer 2: x1 -> x2
    k_gather<<<4096, 256, 0, stream>>>(x1, indptr, cols, cat);
    k_gemm<0><<<512, 256, 0, stream>>>(cat, Wl2, Wr2, b2, x2, NN, 512, 1024, 512);
    k_norm_relu<<<4096, 256, 0, stream>>>(x2);
    // SAGE layer 3: x2 -> x1
    k_gather<<<4096, 256, 0, stream>>>(x2, indptr, cols, cat);
    k_gemm<0><<<512, 256, 0, stream>>>(cat, Wl3, Wr3, b3, x1, NN, 512, 1024, 512);
    k_norm_relu<<<4096, 256, 0, stream>>>(x1);

    // mean pool per graph + linear head
    k_pool<<<128, 256, 0, stream>>>(x1, Wlin, blin, out);
}

// Round 2
// 2212.197 us; speedup vs baseline: 2.9407x; 2.9407x over previous
//
#include <hip/hip_runtime.h>
#include <math.h>

#define NN   16384
#define EE   262144

// ---------------- init (zero barrier/deg/fill) ----------------
__global__ void k_init(int* __restrict__ bar, int* __restrict__ deg, int* __restrict__ fill) {
    int i = blockIdx.x * 256 + threadIdx.x;
    if (i < 128 * 32) bar[i] = 0;
    if (i < NN) { deg[i] = 0; fill[i] = 0; }
}

// ---------------- embedding gather ----------------
__global__ void k_embed(const int* __restrict__ wseq, const float* __restrict__ tab,
                        float* __restrict__ xe) {
    int i = blockIdx.x * 256 + threadIdx.x;
    if (i >= NN * 75) return;              // 300 floats = 75 float4 per row
    int row = i / 75;
    int c = i - row * 75;
    int wid = wseq[row];
    ((float4*)xe)[row * 75 + c] = ((const float4*)tab)[wid * 75 + c];
}

// ---------------- GEMM: C[M][N] = A[M][K] * B + bias ----------------
// TRANSB=1: B1 is (N,K) row-major (B2 unused).
// TRANSB=0: row r<K1 from B1[(K1,N)], else B2[(K-K1,N)].
template<int TRANSB>
__global__ __launch_bounds__(256)
void k_gemm(const float* __restrict__ A, const float* __restrict__ B1,
            const float* __restrict__ B2, const float* __restrict__ bias,
            float* __restrict__ C, int M, int N, int K, int K1)
{
    __shared__ float As[8][132];
    __shared__ float Bs[8][132];
    const int tid = threadIdx.x;
    const int mb = M >> 7;
    const int bm = blockIdx.x % mb;
    const int bn = blockIdx.x / mb;
    const int m0 = bm << 7, n0 = bn << 7;
    const int tx = tid & 15, ty = tid >> 4;

    float acc[8][8];
    #pragma unroll
    for (int i = 0; i < 8; ++i)
        #pragma unroll
        for (int j = 0; j < 8; ++j) acc[i][j] = 0.f;

    for (int k0 = 0; k0 < K; k0 += 8) {
        {   // stage A -> As[k][m]
            int m = tid >> 1, q = (tid & 1) * 4;
            const float* ap = A + (m0 + m) * K + k0 + q;
            float4 v;
            if (k0 + q + 3 < K) v = *(const float4*)ap;
            else {
                v.x = (k0+q+0 < K) ? ap[0] : 0.f;
                v.y = (k0+q+1 < K) ? ap[1] : 0.f;
                v.z = (k0+q+2 < K) ? ap[2] : 0.f;
                v.w = (k0+q+3 < K) ? ap[3] : 0.f;
            }
            As[q+0][m] = v.x; As[q+1][m] = v.y; As[q+2][m] = v.z; As[q+3][m] = v.w;
        }
        if (TRANSB) {   // B1 (N,K): Bs[k][n] = B1[n][k]
            int n = tid >> 1, q = (tid & 1) * 4;
            const float* bp = B1 + (n0 + n) * K + k0 + q;
            float4 v;
            if (k0 + q + 3 < K) v = *(const float4*)bp;
            else {
                v.x = (k0+q+0 < K) ? bp[0] : 0.f;
                v.y = (k0+q+1 < K) ? bp[1] : 0.f;
                v.z = (k0+q+2 < K) ? bp[2] : 0.f;
                v.w = (k0+q+3 < K) ? bp[3] : 0.f;
            }
            Bs[q+0][n] = v.x; Bs[q+1][n] = v.y; Bs[q+2][n] = v.z; Bs[q+3][n] = v.w;
        } else {        // B (K,N) split across B1/B2
            int kk = tid >> 5, nq = (tid & 31) * 4;
            int r = k0 + kk;
            const float* bp = (r < K1) ? (B1 + r * N + n0 + nq)
                                       : (B2 + (r - K1) * N + n0 + nq);
            *(float4*)&Bs[kk][nq] = *(const float4*)bp;
        }
        __syncthreads();
        #pragma unroll
        for (int kk = 0; kk < 8; ++kk) {
            float a[8], b[8];
            *(float4*)&a[0] = *(const float4*)&As[kk][ty*8];
            *(float4*)&a[4] = *(const float4*)&As[kk][ty*8+4];
            *(float4*)&b[0] = *(const float4*)&Bs[kk][tx*8];
            *(float4*)&b[4] = *(const float4*)&Bs[kk][tx*8+4];
            #pragma unroll
            for (int i = 0; i < 8; ++i)
                #pragma unroll
                for (int j = 0; j < 8; ++j)
                    acc[i][j] += a[i] * b[j];
        }
        __syncthreads();
    }
    #pragma unroll
    for (int i = 0; i < 8; ++i) {
        int m = m0 + ty*8 + i;
        float* cp = C + m * N + n0 + tx*8;
        #pragma unroll
        for (int j = 0; j < 8; j += 4) {
            float4 v;
            v.x = acc[i][j+0] + bias[n0 + tx*8 + j+0];
            v.y = acc[i][j+1] + bias[n0 + tx*8 + j+1];
            v.z = acc[i][j+2] + bias[n0 + tx*8 + j+2];
            v.w = acc[i][j+3] + bias[n0 + tx*8 + j+3];
            *(float4*)(cp + j) = v;
        }
    }
}

// ---------------- LSTM recurrence (both directions) ----------------
// grid = 256 wgs: wid = gs*32 + (dir*16 + bs). Group (dir,bs) = 8 wgs
// (all gs) is the complete producer/consumer set for h rows b0..b0+7,
// so only that group barriers each step. whh slice lives in VGPRs
// (128/thread), 8-way K split, partials reduced through LDS.
//
// Sync design (round 2): all cross-wg h traffic via relaxed AGENT-scope
// atomics (sc0/sc1 -> coherence point, bypasses non-coherent per-XCD L2
// both ways). Ordering: h stores -> s_waitcnt vmcnt(0) (per wave) ->
// __syncthreads -> tid0 relaxed atomicAdd on the group's PRIVATE counter
// line (bar[grp*128+t]: 512 B per group, no cross-group line sharing).
// No __threadfence (no L2 writeback/invalidate).
__global__ __launch_bounds__(256, 1)
void k_lstm(const float* __restrict__ xs_f, const float* __restrict__ xs_b,
            const float* __restrict__ whh_f, const float* __restrict__ whh_b,
            float* __restrict__ xout, float* __restrict__ hbuf,
            int* __restrict__ bar)
{
    const int tid = threadIdx.x;
    const int wid = blockIdx.x;
    const int grp = wid & 31;       // dir*16 + bs
    const int gs  = wid >> 5;       // 0..7
    const int dir = grp >> 4;
    const int bs  = grp & 15;
    const int j0 = gs * 32, b0 = bs * 8;
    const float* xs  = dir ? xs_b : xs_f;
    const float* whh = dir ? whh_b : whh_f;
    float* hb = hbuf + dir * (2 * 128 * 256);

    // compute role: ri -> 4 gate-rows, kq -> 32-wide k slice
    const int ri = tid & 31, kq = tid >> 5;
    float wreg[4][32];
    #pragma unroll
    for (int rr = 0; rr < 4; ++rr) {
        int r = 4 * ri + rr;
        int g = r >> 5, jj = r & 31;
        const float* wrow = whh + (g * 256 + j0 + jj) * 256 + kq * 32;
        #pragma unroll
        for (int kk = 0; kk < 32; ++kk) wreg[rr][kk] = wrow[kk];
    }
    // update role: one (hidden j, batch b) cell per thread
    const int jj_u = tid & 31, bb_u = tid >> 5;
    float c_reg = 0.f;

    __shared__ float Hs[8][260];
    __shared__ float ps[8][128][9];

    for (int t = 0; t < 128; ++t) {
        const int l = dir ? (127 - t) : t;
        const int n_u = (b0 + bb_u) * 128 + l;
        const float* xr = xs + n_u * 1024 + j0 + jj_u;
        float xi = xr[0], xf = xr[256], xg = xr[512], xo = xr[768];

        if (t > 0) {
            const float* hsrc = hb + (t & 1) * (128 * 256);
            {   // stage h slice (8 rows x 256) into LDS via coherent loads
                int b = tid >> 5, ks = (tid & 31) * 8;
                const float* hp = hsrc + (b0 + b) * 256 + ks;
                float hv[8];
                #pragma unroll
                for (int q = 0; q < 8; ++q)
                    hv[q] = __hip_atomic_load(hp + q, __ATOMIC_RELAXED,
                                              __HIP_MEMORY_SCOPE_AGENT);
                #pragma unroll
                for (int q = 0; q < 8; ++q) Hs[b][ks + q] = hv[q];
            }
            __syncthreads();
            float accp[4][8];
            #pragma unroll
            for (int rr = 0; rr < 4; ++rr)
                #pragma unroll
                for (int bb = 0; bb < 8; ++bb) accp[rr][bb] = 0.f;
            #pragma unroll
            for (int k4 = 0; k4 < 8; ++k4) {
                #pragma unroll
                for (int bb = 0; bb < 8; ++bb) {
                    float4 h4 = *(const float4*)&Hs[bb][kq * 32 + k4 * 4];
                    #pragma unroll
                    for (int rr = 0; rr < 4; ++rr) {
                        accp[rr][bb] += wreg[rr][k4*4+0] * h4.x
                                      + wreg[rr][k4*4+1] * h4.y
                                      + wreg[rr][k4*4+2] * h4.z
                                      + wreg[rr][k4*4+3] * h4.w;
                    }
                }
            }
            #pragma unroll
            for (int rr = 0; rr < 4; ++rr) {
                int r = 4 * ri + rr;
                #pragma unroll
                for (int bb = 0; bb < 8; ++bb) ps[kq][r][bb] = accp[rr][bb];
            }
        }
        __syncthreads();

        float gi = xi, gf = xf, gg = xg, go = xo;
        if (t > 0) {
            #pragma unroll
            for (int q = 0; q < 8; ++q) {
                gi += ps[q][     jj_u][bb_u];
                gf += ps[q][32 + jj_u][bb_u];
                gg += ps[q][64 + jj_u][bb_u];
                go += ps[q][96 + jj_u][bb_u];
            }
        }
        gi = 1.f / (1.f + expf(-gi));
        gf = 1.f / (1.f + expf(-gf));
        gg = tanhf(gg);
        go = 1.f / (1.f + expf(-go));
        c_reg = gf * c_reg + gi * gg;
        float h = go * tanhf(c_reg);

        xout[n_u * 512 + dir * 256 + j0 + jj_u] = h;
        // cross-wg h exchange: coherent write-through store
        __hip_atomic_store(hb + ((t + 1) & 1) * (128 * 256)
                              + (b0 + bb_u) * 256 + j0 + jj_u,
                           h, __ATOMIC_RELAXED, __HIP_MEMORY_SCOPE_AGENT);

        if (t < 127) {
            // ensure this wave's h stores are acked at the coherence point
            asm volatile("s_waitcnt vmcnt(0)" ::: "memory");
            __syncthreads();           // all 4 waves' stores done
            if (tid == 0) {
                int* bp = bar + grp * 128 + t;   // group-private line
                __hip_atomic_fetch_add(bp, 1, __ATOMIC_RELAXED,
                                       __HIP_MEMORY_SCOPE_AGENT);
                while (__hip_atomic_load(bp, __ATOMIC_RELAXED,
                                         __HIP_MEMORY_SCOPE_AGENT) < 8)
                    __builtin_amdgcn_s_sleep(2);
            }
            __syncthreads();
        }
    }
}

// ---------------- CSR build ----------------
__global__ void k_hist(const int* __restrict__ ei, int* __restrict__ deg) {
    int e = blockIdx.x * 256 + threadIdx.x;
    if (e >= EE) return;
    atomicAdd(&deg[ei[EE + e]], 1);
}

__global__ void k_scan(const int* __restrict__ deg, int* __restrict__ indptr) {
    __shared__ int sm[256];
    int tid = threadIdx.x;
    int b0 = tid * 64;
    int s = 0;
    for (int i = 0; i < 64; ++i) s += deg[b0 + i];
    sm[tid] = s;
    __syncthreads();
    for (int off = 1; off < 256; off <<= 1) {
        int v = (tid >= off) ? sm[tid - off] : 0;
        __syncthreads();
        sm[tid] += v;
        __syncthreads();
    }
    int run = sm[tid] - s;   // exclusive prefix
    for (int i = 0; i < 64; ++i) { indptr[b0 + i] = run; run += deg[b0 + i]; }
    if (tid == 255) indptr[NN] = run;
}

__global__ void k_scatter(const int* __restrict__ ei, const int* __restrict__ indptr,
                          int* __restrict__ fill, int* __restrict__ cols) {
    int e = blockIdx.x * 256 + threadIdx.x;
    if (e >= EE) return;
    int d = ei[EE + e];
    int slot = atomicAdd(&fill[d], 1);
    cols[indptr[d] + slot] = ei[e];
}

// ---------------- SAGE neighbor mean + concat ----------------
// one wave per dst node; cat[n] = [agg(n) (512) | x(n) (512)]
__global__ __launch_bounds__(256)
void k_gather(const float* __restrict__ x, const int* __restrict__ indptr,
              const int* __restrict__ cols, float* __restrict__ cat)
{
    int gw = (blockIdx.x * 256 + threadIdx.x) >> 6;
    int lane = threadIdx.x & 63;
    if (gw >= NN) return;
    int s = indptr[gw], e = indptr[gw + 1];
    float a0=0,a1=0,a2=0,a3=0,a4=0,a5=0,a6=0,a7=0;
    for (int p = s; p < e; ++p) {
        const float4* xp = (const float4*)(x + cols[p] * 512 + lane * 8);
        float4 v0 = xp[0], v1 = xp[1];
        a0 += v0.x; a1 += v0.y; a2 += v0.z; a3 += v0.w;
        a4 += v1.x; a5 += v1.y; a6 += v1.z; a7 += v1.w;
    }
    float sc = 1.f / (float)((e - s) > 1 ? (e - s) : 1);
    float* cp = cat + gw * 1024 + lane * 8;
    float4 o0 = { a0*sc, a1*sc, a2*sc, a3*sc };
    float4 o1 = { a4*sc, a5*sc, a6*sc, a7*sc };
    *(float4*)cp = o0;
    *(float4*)(cp + 4) = o1;
    const float4* xp = (const float4*)(x + gw * 512 + lane * 8);
    *(float4*)(cp + 512) = xp[0];
    *(float4*)(cp + 516) = xp[1];
}

// ---------------- row L2-normalize + relu (in place) ----------------
__global__ __launch_bounds__(256)
void k_norm_relu(float* __restrict__ y)
{
    int gw = (blockIdx.x * 256 + threadIdx.x) >> 6;
    int lane = threadIdx.x & 63;
    if (gw >= NN) return;
    float* row = y + gw * 512 + lane * 8;
    float4 v0 = *(const float4*)row;
    float4 v1 = *(const float4*)(row + 4);
    float ss = v0.x*v0.x + v0.y*v0.y + v0.z*v0.z + v0.w*v0.w
             + v1.x*v1.x + v1.y*v1.y + v1.z*v1.z + v1.w*v1.w;
    #pragma unroll
    for (int off = 32; off >= 1; off >>= 1) ss += __shfl_xor(ss, off);
    float sc = 1.f / fmaxf(sqrtf(ss), 1e-12f);
    float4 o0, o1;
    o0.x = fmaxf(v0.x*sc, 0.f); o0.y = fmaxf(v0.y*sc, 0.f);
    o0.z = fmaxf(v0.z*sc, 0.f); o0.w = fmaxf(v0.w*sc, 0.f);
    o1.x = fmaxf(v1.x*sc, 0.f); o1.y = fmaxf(v1.y*sc, 0.f);
    o1.z = fmaxf(v1.z*sc, 0.f); o1.w = fmaxf(v1.w*sc, 0.f);
    *(float4*)row = o0;
    *(float4*)(row + 4) = o1;
}

// ---------------- mean-pool per graph + linear head ----------------
__global__ __launch_bounds__(256)
void k_pool(const float* __restrict__ x, const float* __restrict__ Wlin,
            const float* __restrict__ blin, float* __restrict__ out)
{
    int g = blockIdx.x;
    int tid = threadIdx.x;
    const float* base = x + g * 128 * 512;
    float a0 = 0.f, a1 = 0.f;
    for (int r = 0; r < 128; ++r) {
        a0 += base[r * 512 + 2*tid];
        a1 += base[r * 512 + 2*tid + 1];
    }
    __shared__ float pooled[512];
    pooled[2*tid]     = a0 * (1.f / 128.f);
    pooled[2*tid + 1] = a1 * (1.f / 128.f);
    __syncthreads();
    if (tid < 64) {
        float p0 = 0.f, p1 = 0.f;
        for (int k = tid; k < 512; k += 64) {
            float pv = pooled[k];
            p0 += pv * Wlin[2*k];
            p1 += pv * Wlin[2*k + 1];
        }
        #pragma unroll
        for (int off = 32; off >= 1; off >>= 1) {
            p0 += __shfl_xor(p0, off);
            p1 += __shfl_xor(p1, off);
        }
        if (tid == 0) {
            out[2*g]     = p0 + blin[0];
            out[2*g + 1] = p1 + blin[1];
        }
    }
}

extern "C" void kernel_launch(void* const* d_in, const int* in_sizes, int n_in,
                              void* d_out, int out_size, void* d_ws, size_t ws_size,
                              hipStream_t stream)
{
    (void)in_sizes; (void)n_in; (void)out_size; (void)ws_size;
    const int*   word_seq = (const int*)  d_in[0];
    const int*   ei       = (const int*)  d_in[1];
    const float* tab      = (const float*)d_in[3];
    const float* wih_f    = (const float*)d_in[4];
    const float* whh_f    = (const float*)d_in[5];
    const float* b_f      = (const float*)d_in[6];
    const float* wih_b    = (const float*)d_in[7];
    const float* whh_b    = (const float*)d_in[8];
    const float* b_b      = (const float*)d_in[9];
    const float* Wl1      = (const float*)d_in[10];
    const float* Wr1      = (const float*)d_in[11];
    const float* b1       = (const float*)d_in[12];
    const float* Wl2      = (const float*)d_in[13];
    const float* Wr2      = (const float*)d_in[14];
    const float* b2       = (const float*)d_in[15];
    const float* Wl3      = (const float*)d_in[16];
    const float* Wr3      = (const float*)d_in[17];
    const float* b3       = (const float*)d_in[18];
    const float* Wlin     = (const float*)d_in[19];
    const float* blin     = (const float*)d_in[20];
    float* out = (float*)d_out;

    char* w = (char*)d_ws;
    // region 0 (reused): xe lives here until proj GEMMs finish, then CSR/barrier/hbuf
    float* xe     = (float*)(w);                    // 19,660,800 B
    int*   bar    = (int*)  (w);                    //     16,384 B
    int*   deg    = (int*)  (w + 16384);            //     65,536 B
    int*   indptr = (int*)  (w + 81920);            //     66,048 B
    int*   fill   = (int*)  (w + 147968);           //     65,536 B
    int*   cols   = (int*)  (w + 213504);           //  1,048,576 B
    float* hbuf   = (float*)(w + 1262080);          //  1,048,576 B
    float* xs_f   = (float*)(w + 19660800);         // 67,108,864 B
    float* xs_b   = (float*)(w + 86769664);         // 67,108,864 B
    float* x0     = (float*)(w + 153878528);        // 33,554,432 B  (end ~179 MB)
    float* cat    = xs_f;                           // reuse after LSTM
    float* x1     = xs_b;                           // reuse after LSTM
    float* x2     = (float*)((char*)xs_b + 33554432);

    // embedding + LSTM input projections (xe live)
    k_embed<<<4800, 256, 0, stream>>>(word_seq, tab, xe);
    k_gemm<1><<<1024, 256, 0, stream>>>(xe, wih_f, nullptr, b_f, xs_f, NN, 1024, 300, 300);
    k_gemm<1><<<1024, 256, 0, stream>>>(xe, wih_b, nullptr, b_b, xs_b, NN, 1024, 300, 300);

    // CSR build (overwrites xe region — xe dead now)
    k_init<<<64, 256, 0, stream>>>(bar, deg, fill);
    k_hist<<<1024, 256, 0, stream>>>(ei, deg);
    k_scan<<<1, 256, 0, stream>>>(deg, indptr);
    k_scatter<<<1024, 256, 0, stream>>>(ei, indptr, fill, cols);

    // bidirectional LSTM scan -> x0 = [hf | hb]
    k_lstm<<<256, 256, 0, stream>>>(xs_f, xs_b, whh_f, whh_b, x0, hbuf, bar);

    // SAGE layer 1: x0 -> x1
    k_gather<<<4096, 256, 0, stream>>>(x0, indptr, cols, cat);
    k_gemm<0><<<512, 256, 0, stream>>>(cat, Wl1, Wr1, b1, x1, NN, 512, 1024, 512);
    k_norm_relu<<<4096, 256, 0, stream>>>(x1);
    // SAGE layer 2: x1 -> x2
    k_gather<<<4096, 256, 0, stream>>>(x1, indptr, cols, cat);
    k_gemm<0><<<512, 256, 0, stream>>>(cat, Wl2, Wr2, b2, x2, NN, 512, 1024, 512);
    k_norm_relu<<<4096, 256, 0, stream>>>(x2);
    // SAGE layer 3: x2 -> x1
    k_gather<<<4096, 256, 0, stream>>>(x2, indptr, cols, cat);
    k_gemm<0><<<512, 256, 0, stream>>>(cat, Wl3, Wr3, b3, x1, NN, 512, 1024, 512);
    k_norm_relu<<<4096, 256, 0, stream>>>(x1);

    // mean pool per graph + linear head
    k_pool<<<128, 256, 0, stream>>>(x1, Wlin, blin, out);
}

// Round 3
// 1406.038 us; speedup vs baseline: 4.6267x; 1.5734x over previous
//
#include <hip/hip_runtime.h>
#include <math.h>

#define NN   16384
#define EE   262144

typedef __attribute__((ext_vector_type(8))) short  short8v;   // 8 bf16 = 4 VGPR
typedef __attribute__((ext_vector_type(4))) float  f32x4;

__device__ inline unsigned short f2bf(float f) {
    union { float f; unsigned u; } v; v.f = f;
    unsigned r = v.u + 0x7fff + ((v.u >> 16) & 1);   // RNE
    return (unsigned short)(r >> 16);
}

// ---------------- init (zero barrier/deg/fill) ----------------
__global__ void k_init(int* __restrict__ bar, int* __restrict__ deg, int* __restrict__ fill) {
    int i = blockIdx.x * 256 + threadIdx.x;
    if (i < 128 * 32) bar[i] = 0;
    if (i < NN) { deg[i] = 0; fill[i] = 0; }
}

// ---------------- embedding gather -> bf16, K padded 300->320 ----------------
__global__ void k_embed_bf(const int* __restrict__ wseq, const float* __restrict__ tab,
                           unsigned short* __restrict__ xeb) {
    int i = blockIdx.x * 256 + threadIdx.x;
    if (i >= NN * 320) return;
    int row = i / 320, k = i - row * 320;
    float f = (k < 300) ? tab[wseq[row] * 300 + k] : 0.f;
    xeb[i] = f2bf(f);
}

// ---------------- weight conversions ----------------
// wih (1024,300) fp32 -> wt (1024,320) bf16 (already N-major)
__global__ void k_cvt_wih(const float* __restrict__ wih, unsigned short* __restrict__ wt) {
    int i = blockIdx.x * 256 + threadIdx.x;
    if (i >= 1024 * 320) return;
    int n = i / 320, k = i - n * 320;
    wt[i] = f2bf(k < 300 ? wih[n * 300 + k] : 0.f);
}
// Wl,Wr (512,512) fp32 -> wc (512,1024) bf16: wc[n][k] = k<512 ? Wl[k][n] : Wr[k-512][n]
__global__ void k_cvt_wcat(const float* __restrict__ Wl, const float* __restrict__ Wr,
                           unsigned short* __restrict__ wc) {
    int i = blockIdx.x * 256 + threadIdx.x;
    if (i >= 512 * 1024) return;
    int n = i >> 10, k = i & 1023;
    float f = (k < 512) ? Wl[k * 512 + n] : Wr[(k - 512) * 512 + n];
    wc[i] = f2bf(f);
}

// ---------------- bf16 MFMA GEMM: C[M][N] = A[M][Ka] * Bt[N][Ka]^T + bias ----------------
// 128x128 tile, 4 waves in 2x2 (each 64x64 = 4x4 frags of 16x16x32).
// A-frag: lane holds A[row=l&15][k=(l>>4)*8 + e]  (contiguous 8 -> ds_read_b128)
// B-frag: lane holds B[k=(l>>4)*8+e][col=l&15] = Bt[col][k]
// C/D:    col=lane&15, row=(lane>>4)*4+reg   [m89-verified]
__global__ __launch_bounds__(256)
void k_mgemm(const unsigned short* __restrict__ A, const unsigned short* __restrict__ Bt,
             const float* __restrict__ bias, float* __restrict__ C, int N, int Ka)
{
    __shared__ unsigned short As[128 * 32];
    __shared__ unsigned short Bs[128 * 32];
    const int tid = threadIdx.x;
    const int m0 = blockIdx.x << 7, n0 = blockIdx.y << 7;
    const int w = tid >> 6, lane = tid & 63;
    const int wr = w >> 1, wc = w & 1;
    const int lr = lane & 15, lhi = lane >> 4;
    const int r0 = tid >> 2, kc0 = (tid & 3) * 8;   // staging: 16B chunk per thread, x2

    f32x4 acc[4][4] = {};

    for (int k0 = 0; k0 < Ka; k0 += 32) {
        short8v a0 = *(const short8v*)(A + (m0 + r0) * Ka + k0 + kc0);
        short8v a1 = *(const short8v*)(A + (m0 + 64 + r0) * Ka + k0 + kc0);
        short8v b0 = *(const short8v*)(Bt + (n0 + r0) * Ka + k0 + kc0);
        short8v b1 = *(const short8v*)(Bt + (n0 + 64 + r0) * Ka + k0 + kc0);
        __syncthreads();                       // prev iter's frag reads done
        *(short8v*)&As[r0 * 32 + kc0]        = a0;
        *(short8v*)&As[(64 + r0) * 32 + kc0] = a1;
        *(short8v*)&Bs[r0 * 32 + kc0]        = b0;
        *(short8v*)&Bs[(64 + r0) * 32 + kc0] = b1;
        __syncthreads();
        short8v af[4], bf[4];
        #pragma unroll
        for (int i = 0; i < 4; ++i)
            af[i] = *(const short8v*)&As[(wr * 64 + i * 16 + lr) * 32 + lhi * 8];
        #pragma unroll
        for (int j = 0; j < 4; ++j)
            bf[j] = *(const short8v*)&Bs[(wc * 64 + j * 16 + lr) * 32 + lhi * 8];
        #pragma unroll
        for (int i = 0; i < 4; ++i)
            #pragma unroll
            for (int j = 0; j < 4; ++j)
                acc[i][j] = __builtin_amdgcn_mfma_f32_16x16x32_bf16(af[i], bf[j], acc[i][j], 0, 0, 0);
    }
    #pragma unroll
    for (int i = 0; i < 4; ++i) {
        int row = m0 + wr * 64 + i * 16 + lhi * 4;
        #pragma unroll
        for (int j = 0; j < 4; ++j) {
            int col = n0 + wc * 64 + j * 16 + lr;
            float bv = bias[col];
            #pragma unroll
            for (int r = 0; r < 4; ++r)
                C[(row + r) * N + col] = acc[i][j][r] + bv;
        }
    }
}

// ---------------- LSTM recurrence (both directions) ----------------
__global__ __launch_bounds__(256, 1)
void k_lstm(const float* __restrict__ xs_f, const float* __restrict__ xs_b,
            const float* __restrict__ whh_f, const float* __restrict__ whh_b,
            float* __restrict__ xout, float* __restrict__ hbuf,
            int* __restrict__ bar)
{
    const int tid = threadIdx.x;
    const int wid = blockIdx.x;
    const int grp = wid & 31;       // dir*16 + bs
    const int gs  = wid >> 5;       // 0..7
    const int dir = grp >> 4;
    const int bs  = grp & 15;
    const int j0 = gs * 32, b0 = bs * 8;
    const float* xs  = dir ? xs_b : xs_f;
    const float* whh = dir ? whh_b : whh_f;
    float* hb = hbuf + dir * (2 * 128 * 256);

    const int ri = tid & 31, kq = tid >> 5;
    float wreg[4][32];
    #pragma unroll
    for (int rr = 0; rr < 4; ++rr) {
        int r = 4 * ri + rr;
        int g = r >> 5, jj = r & 31;
        const float* wrow = whh + (g * 256 + j0 + jj) * 256 + kq * 32;
        #pragma unroll
        for (int kk = 0; kk < 32; ++kk) wreg[rr][kk] = wrow[kk];
    }
    const int jj_u = tid & 31, bb_u = tid >> 5;
    float c_reg = 0.f;

    __shared__ float Hs[8][260];
    __shared__ float ps[8][128][9];

    // preload x(t=0)
    {
        const int l0 = dir ? 127 : 0;
        (void)l0;
    }
    const float* xr0 = xs + ((b0 + bb_u) * 128 + (dir ? 127 : 0)) * 1024 + j0 + jj_u;
    float xi = xr0[0], xf = xr0[256], xg = xr0[512], xo = xr0[768];

    for (int t = 0; t < 128; ++t) {
        const int l = dir ? (127 - t) : t;
        const int n_u = (b0 + bb_u) * 128 + l;

        if (t > 0) {
            const float* hsrc = hb + (t & 1) * (128 * 256);
            {   // stage h slice (8 rows x 256) into LDS via coherent loads
                int b = tid >> 5, ks = (tid & 31) * 8;
                const float* hp = hsrc + (b0 + b) * 256 + ks;
                float hv[8];
                #pragma unroll
                for (int q = 0; q < 8; ++q)
                    hv[q] = __hip_atomic_load(hp + q, __ATOMIC_RELAXED,
                                              __HIP_MEMORY_SCOPE_AGENT);
                #pragma unroll
                for (int q = 0; q < 8; ++q) Hs[b][ks + q] = hv[q];
            }
            __syncthreads();
            float accp[4][8];
            #pragma unroll
            for (int rr = 0; rr < 4; ++rr)
                #pragma unroll
                for (int bb = 0; bb < 8; ++bb) accp[rr][bb] = 0.f;
            #pragma unroll
            for (int k4 = 0; k4 < 8; ++k4) {
                #pragma unroll
                for (int bb = 0; bb < 8; ++bb) {
                    float4 h4 = *(const float4*)&Hs[bb][kq * 32 + k4 * 4];
                    #pragma unroll
                    for (int rr = 0; rr < 4; ++rr) {
                        accp[rr][bb] += wreg[rr][k4*4+0] * h4.x
                                      + wreg[rr][k4*4+1] * h4.y
                                      + wreg[rr][k4*4+2] * h4.z
                                      + wreg[rr][k4*4+3] * h4.w;
                    }
                }
            }
            #pragma unroll
            for (int rr = 0; rr < 4; ++rr) {
                int r = 4 * ri + rr;
                #pragma unroll
                for (int bb = 0; bb < 8; ++bb) ps[kq][r][bb] = accp[rr][bb];
            }
        }
        __syncthreads();

        float gi = xi, gf = xf, gg = xg, go = xo;
        if (t > 0) {
            #pragma unroll
            for (int q = 0; q < 8; ++q) {
                gi += ps[q][     jj_u][bb_u];
                gf += ps[q][32 + jj_u][bb_u];
                gg += ps[q][64 + jj_u][bb_u];
                go += ps[q][96 + jj_u][bb_u];
            }
        }
        gi = 1.f / (1.f + expf(-gi));
        gf = 1.f / (1.f + expf(-gf));
        gg = tanhf(gg);
        go = 1.f / (1.f + expf(-go));
        c_reg = gf * c_reg + gi * gg;
        float h = go * tanhf(c_reg);

        xout[n_u * 512 + dir * 256 + j0 + jj_u] = h;
        __hip_atomic_store(hb + ((t + 1) & 1) * (128 * 256)
                              + (b0 + bb_u) * 256 + j0 + jj_u,
                           h, __ATOMIC_RELAXED, __HIP_MEMORY_SCOPE_AGENT);

        if (t < 127) {
            // prefetch x(t+1): in flight alongside h-store ack, both drained by vmcnt(0)
            const int l2 = dir ? (126 - t) : (t + 1);
            const float* xr2 = xs + ((b0 + bb_u) * 128 + l2) * 1024 + j0 + jj_u;
            xi = xr2[0]; xf = xr2[256]; xg = xr2[512]; xo = xr2[768];
            asm volatile("s_waitcnt vmcnt(0)" ::: "memory");
            __syncthreads();
            if (tid == 0) {
                int* bp = bar + grp * 128 + t;   // group-private line
                __hip_atomic_fetch_add(bp, 1, __ATOMIC_RELAXED,
                                       __HIP_MEMORY_SCOPE_AGENT);
                while (__hip_atomic_load(bp, __ATOMIC_RELAXED,
                                         __HIP_MEMORY_SCOPE_AGENT) < 8)
                    __builtin_amdgcn_s_sleep(1);
            }
            __syncthreads();
        }
    }
}

// ---------------- CSR build ----------------
__global__ void k_hist(const int* __restrict__ ei, int* __restrict__ deg) {
    int e = blockIdx.x * 256 + threadIdx.x;
    if (e >= EE) return;
    atomicAdd(&deg[ei[EE + e]], 1);
}

__global__ void k_scan(const int* __restrict__ deg, int* __restrict__ indptr) {
    __shared__ int sm[256];
    int tid = threadIdx.x;
    int b0 = tid * 64;
    int s = 0;
    for (int i = 0; i < 64; ++i) s += deg[b0 + i];
    sm[tid] = s;
    __syncthreads();
    for (int off = 1; off < 256; off <<= 1) {
        int v = (tid >= off) ? sm[tid - off] : 0;
        __syncthreads();
        sm[tid] += v;
        __syncthreads();
    }
    int run = sm[tid] - s;   // exclusive prefix
    for (int i = 0; i < 64; ++i) { indptr[b0 + i] = run; run += deg[b0 + i]; }
    if (tid == 255) indptr[NN] = run;
}

__global__ void k_scatter(const int* __restrict__ ei, const int* __restrict__ indptr,
                          int* __restrict__ fill, int* __restrict__ cols) {
    int e = blockIdx.x * 256 + threadIdx.x;
    if (e >= EE) return;
    int d = ei[EE + e];
    int slot = atomicAdd(&fill[d], 1);
    cols[indptr[d] + slot] = ei[e];
}

// ---------------- SAGE neighbor mean + concat -> bf16 ----------------
__global__ __launch_bounds__(256)
void k_gather(const float* __restrict__ x, const int* __restrict__ indptr,
              const int* __restrict__ cols, unsigned short* __restrict__ catb)
{
    int gw = (blockIdx.x * 256 + threadIdx.x) >> 6;
    int lane = threadIdx.x & 63;
    if (gw >= NN) return;
    int s = indptr[gw], e = indptr[gw + 1];
    float a0=0,a1=0,a2=0,a3=0,a4=0,a5=0,a6=0,a7=0;
    for (int p = s; p < e; ++p) {
        const float4* xp = (const float4*)(x + cols[p] * 512 + lane * 8);
        float4 v0 = xp[0], v1 = xp[1];
        a0 += v0.x; a1 += v0.y; a2 += v0.z; a3 += v0.w;
        a4 += v1.x; a5 += v1.y; a6 += v1.z; a7 += v1.w;
    }
    float sc = 1.f / (float)((e - s) > 1 ? (e - s) : 1);
    unsigned short* cp = catb + gw * 1024 + lane * 8;
    unsigned short o[8];
    o[0]=f2bf(a0*sc); o[1]=f2bf(a1*sc); o[2]=f2bf(a2*sc); o[3]=f2bf(a3*sc);
    o[4]=f2bf(a4*sc); o[5]=f2bf(a5*sc); o[6]=f2bf(a6*sc); o[7]=f2bf(a7*sc);
    *(short8v*)cp = *(short8v*)o;
    const float4* xp = (const float4*)(x + gw * 512 + lane * 8);
    float4 v0 = xp[0], v1 = xp[1];
    o[0]=f2bf(v0.x); o[1]=f2bf(v0.y); o[2]=f2bf(v0.z); o[3]=f2bf(v0.w);
    o[4]=f2bf(v1.x); o[5]=f2bf(v1.y); o[6]=f2bf(v1.z); o[7]=f2bf(v1.w);
    *(short8v*)(cp + 512) = *(short8v*)o;
}

// ---------------- row L2-normalize + relu (in place) ----------------
__global__ __launch_bounds__(256)
void k_norm_relu(float* __restrict__ y)
{
    int gw = (blockIdx.x * 256 + threadIdx.x) >> 6;
    int lane = threadIdx.x & 63;
    if (gw >= NN) return;
    float* row = y + gw * 512 + lane * 8;
    float4 v0 = *(const float4*)row;
    float4 v1 = *(const float4*)(row + 4);
    float ss = v0.x*v0.x + v0.y*v0.y + v0.z*v0.z + v0.w*v0.w
             + v1.x*v1.x + v1.y*v1.y + v1.z*v1.z + v1.w*v1.w;
    #pragma unroll
    for (int off = 32; off >= 1; off >>= 1) ss += __shfl_xor(ss, off);
    float sc = 1.f / fmaxf(sqrtf(ss), 1e-12f);
    float4 o0, o1;
    o0.x = fmaxf(v0.x*sc, 0.f); o0.y = fmaxf(v0.y*sc, 0.f);
    o0.z = fmaxf(v0.z*sc, 0.f); o0.w = fmaxf(v0.w*sc, 0.f);
    o1.x = fmaxf(v1.x*sc, 0.f); o1.y = fmaxf(v1.y*sc, 0.f);
    o1.z = fmaxf(v1.z*sc, 0.f); o1.w = fmaxf(v1.w*sc, 0.f);
    *(float4*)row = o0;
    *(float4*)(row + 4) = o1;
}

// ---------------- mean-pool per graph + linear head ----------------
__global__ __launch_bounds__(256)
void k_pool(const float* __restrict__ x, const float* __restrict__ Wlin,
            const float* __restrict__ blin, float* __restrict__ out)
{
    int g = blockIdx.x;
    int tid = threadIdx.x;
    const float* base = x + g * 128 * 512;
    float a0 = 0.f, a1 = 0.f;
    for (int r = 0; r < 128; ++r) {
        a0 += base[r * 512 + 2*tid];
        a1 += base[r * 512 + 2*tid + 1];
    }
    __shared__ float pooled[512];
    pooled[2*tid]     = a0 * (1.f / 128.f);
    pooled[2*tid + 1] = a1 * (1.f / 128.f);
    __syncthreads();
    if (tid < 64) {
        float p0 = 0.f, p1 = 0.f;
        for (int k = tid; k < 512; k += 64) {
            float pv = pooled[k];
            p0 += pv * Wlin[2*k];
            p1 += pv * Wlin[2*k + 1];
        }
        #pragma unroll
        for (int off = 32; off >= 1; off >>= 1) {
            p0 += __shfl_xor(p0, off);
            p1 += __shfl_xor(p1, off);
        }
        if (tid == 0) {
            out[2*g]     = p0 + blin[0];
            out[2*g + 1] = p1 + blin[1];
        }
    }
}

extern "C" void kernel_launch(void* const* d_in, const int* in_sizes, int n_in,
                              void* d_out, int out_size, void* d_ws, size_t ws_size,
                              hipStream_t stream)
{
    (void)in_sizes; (void)n_in; (void)out_size; (void)ws_size;
    const int*   word_seq = (const int*)  d_in[0];
    const int*   ei       = (const int*)  d_in[1];
    const float* tab      = (const float*)d_in[3];
    const float* wih_f    = (const float*)d_in[4];
    const float* whh_f    = (const float*)d_in[5];
    const float* b_f      = (const float*)d_in[6];
    const float* wih_b    = (const float*)d_in[7];
    const float* whh_b    = (const float*)d_in[8];
    const float* b_b      = (const float*)d_in[9];
    const float* Wl1      = (const float*)d_in[10];
    const float* Wr1      = (const float*)d_in[11];
    const float* b1       = (const float*)d_in[12];
    const float* Wl2      = (const float*)d_in[13];
    const float* Wr2      = (const float*)d_in[14];
    const float* b2       = (const float*)d_in[15];
    const float* Wl3      = (const float*)d_in[16];
    const float* Wr3      = (const float*)d_in[17];
    const float* b3       = (const float*)d_in[18];
    const float* Wlin     = (const float*)d_in[19];
    const float* blin     = (const float*)d_in[20];
    float* out = (float*)d_out;

    char* w = (char*)d_ws;
    int*   bar    = (int*)  (w);                    //     16,384
    int*   deg    = (int*)  (w + 16384);            //     65,536
    int*   indptr = (int*)  (w + 81920);            //     66,048
    int*   fill   = (int*)  (w + 147968);           //     65,536
    int*   cols   = (int*)  (w + 213504);           //  1,048,576
    float* hbuf   = (float*)(w + 1262080);          //  1,048,576
    unsigned short* wt_f = (unsigned short*)(w + 2310656);   // 655,360
    unsigned short* wt_b = (unsigned short*)(w + 2966016);   // 655,360
    unsigned short* wc1  = (unsigned short*)(w + 3621376);   // 1,048,576
    unsigned short* wc2  = (unsigned short*)(w + 4669952);   // 1,048,576
    unsigned short* wc3  = (unsigned short*)(w + 5718528);   // 1,048,576
    unsigned short* xeb  = (unsigned short*)(w + 6767104);   // 10,485,760
    float* xs_f   = (float*)(w + 17252864);         // 67,108,864
    float* xs_b   = (float*)(w + 84361728);         // 67,108,864
    float* x0     = (float*)(w + 151470592);        // 33,554,432 (end ~185.0 MB)
    unsigned short* catb = (unsigned short*)(w + 17252864);  // reuse xs_f[0:32M]
    float* x1     = (float*)(w + 50807296);         // reuse xs_f[32M:64M]
    float* x2     = (float*)(w + 84361728);         // reuse xs_b[0:32M]

    // conversions + embedding (bf16)
    k_embed_bf<<<20480, 256, 0, stream>>>(word_seq, tab, xeb);
    k_cvt_wih<<<1280, 256, 0, stream>>>(wih_f, wt_f);
    k_cvt_wih<<<1280, 256, 0, stream>>>(wih_b, wt_b);
    k_cvt_wcat<<<2048, 256, 0, stream>>>(Wl1, Wr1, wc1);
    k_cvt_wcat<<<2048, 256, 0, stream>>>(Wl2, Wr2, wc2);
    k_cvt_wcat<<<2048, 256, 0, stream>>>(Wl3, Wr3, wc3);

    // CSR build
    k_init<<<64, 256, 0, stream>>>(bar, deg, fill);
    k_hist<<<1024, 256, 0, stream>>>(ei, deg);
    k_scan<<<1, 256, 0, stream>>>(deg, indptr);
    k_scatter<<<1024, 256, 0, stream>>>(ei, indptr, fill, cols);

    // LSTM input projections (bf16 MFMA): xs = xeb @ wt^T + b
    k_mgemm<<<dim3(128, 8), 256, 0, stream>>>(xeb, wt_f, b_f, xs_f, 1024, 320);
    k_mgemm<<<dim3(128, 8), 256, 0, stream>>>(xeb, wt_b, b_b, xs_b, 1024, 320);

    // bidirectional LSTM scan -> x0 = [hf | hb]
    k_lstm<<<256, 256, 0, stream>>>(xs_f, xs_b, whh_f, whh_b, x0, hbuf, bar);

    // SAGE layer 1
    k_gather<<<4096, 256, 0, stream>>>(x0, indptr, cols, catb);
    k_mgemm<<<dim3(128, 4), 256, 0, stream>>>(catb, wc1, b1, x1, 512, 1024);
    k_norm_relu<<<4096, 256, 0, stream>>>(x1);
    // SAGE layer 2
    k_gather<<<4096, 256, 0, stream>>>(x1, indptr, cols, catb);
    k_mgemm<<<dim3(128, 4), 256, 0, stream>>>(catb, wc2, b2, x2, 512, 1024);
    k_norm_relu<<<4096, 256, 0, stream>>>(x2);
    // SAGE layer 3
    k_gather<<<4096, 256, 0, stream>>>(x2, indptr, cols, catb);
    k_mgemm<<<dim3(128, 4), 256, 0, stream>>>(catb, wc3, b3, x1, 512, 1024);
    k_norm_relu<<<4096, 256, 0, stream>>>(x1);

    // mean pool per graph + linear head
    k_pool<<<128, 256, 0, stream>>>(x1, Wlin, blin, out);
}

// Round 4
// 1344.581 us; speedup vs baseline: 4.8382x; 1.0457x over previous
//
#include <hip/hip_runtime.h>
#include <math.h>

#define NN   16384
#define EE   262144

typedef __attribute__((ext_vector_type(8))) short  short8v;   // 8 bf16 = 4 VGPR
typedef __attribute__((ext_vector_type(4))) float  f32x4;

__device__ inline unsigned short f2bf(float f) {
    union { float f; unsigned u; } v; v.f = f;
    unsigned r = v.u + 0x7fff + ((v.u >> 16) & 1);   // RNE
    return (unsigned short)(r >> 16);
}
__device__ inline float bf2f(unsigned short b) {
    unsigned u = ((unsigned)b) << 16;
    union { unsigned u; float f; } v; v.u = u; return v.f;
}

// ---------------- init (zero hbuf tags / deg / fill) ----------------
__global__ void k_init(unsigned long long* __restrict__ hbuf, int* __restrict__ deg,
                       int* __restrict__ fill) {
    int i = blockIdx.x * 256 + threadIdx.x;
    if (i < 2 * 2 * 128 * 256) hbuf[i] = 0ull;      // tag=0 != any wanted tag (>=1)
    if (i < NN) { deg[i] = 0; fill[i] = 0; }
}

// ---------------- embedding gather -> bf16, K padded 300->320 ----------------
__global__ void k_embed_bf(const int* __restrict__ wseq, const float* __restrict__ tab,
                           unsigned short* __restrict__ xeb) {
    int i = blockIdx.x * 256 + threadIdx.x;
    if (i >= NN * 320) return;
    int row = i / 320, k = i - row * 320;
    float f = (k < 300) ? tab[wseq[row] * 300 + k] : 0.f;
    xeb[i] = f2bf(f);
}

// ---------------- weight conversions ----------------
__global__ void k_cvt_wih(const float* __restrict__ wih, unsigned short* __restrict__ wt) {
    int i = blockIdx.x * 256 + threadIdx.x;
    if (i >= 1024 * 320) return;
    int n = i / 320, k = i - n * 320;
    wt[i] = f2bf(k < 300 ? wih[n * 300 + k] : 0.f);
}
__global__ void k_cvt_wcat(const float* __restrict__ Wl, const float* __restrict__ Wr,
                           unsigned short* __restrict__ wc) {
    int i = blockIdx.x * 256 + threadIdx.x;
    if (i >= 512 * 1024) return;
    int n = i >> 10, k = i & 1023;
    float f = (k < 512) ? Wl[k * 512 + n] : Wr[(k - 512) * 512 + n];
    wc[i] = f2bf(f);
}

// ---------------- bf16 MFMA GEMM: C[M][N] = A[M][Ka] * Bt[N][Ka]^T + bias ----------------
__global__ __launch_bounds__(256)
void k_mgemm(const unsigned short* __restrict__ A, const unsigned short* __restrict__ Bt,
             const float* __restrict__ bias, float* __restrict__ C, int N, int Ka)
{
    __shared__ unsigned short As[128 * 32];
    __shared__ unsigned short Bs[128 * 32];
    const int tid = threadIdx.x;
    const int m0 = blockIdx.x << 7, n0 = blockIdx.y << 7;
    const int w = tid >> 6, lane = tid & 63;
    const int wr = w >> 1, wc = w & 1;
    const int lr = lane & 15, lhi = lane >> 4;
    const int r0 = tid >> 2, kc0 = (tid & 3) * 8;

    f32x4 acc[4][4] = {};

    for (int k0 = 0; k0 < Ka; k0 += 32) {
        short8v a0 = *(const short8v*)(A + (m0 + r0) * Ka + k0 + kc0);
        short8v a1 = *(const short8v*)(A + (m0 + 64 + r0) * Ka + k0 + kc0);
        short8v b0 = *(const short8v*)(Bt + (n0 + r0) * Ka + k0 + kc0);
        short8v b1 = *(const short8v*)(Bt + (n0 + 64 + r0) * Ka + k0 + kc0);
        __syncthreads();
        *(short8v*)&As[r0 * 32 + kc0]        = a0;
        *(short8v*)&As[(64 + r0) * 32 + kc0] = a1;
        *(short8v*)&Bs[r0 * 32 + kc0]        = b0;
        *(short8v*)&Bs[(64 + r0) * 32 + kc0] = b1;
        __syncthreads();
        short8v af[4], bf[4];
        #pragma unroll
        for (int i = 0; i < 4; ++i)
            af[i] = *(const short8v*)&As[(wr * 64 + i * 16 + lr) * 32 + lhi * 8];
        #pragma unroll
        for (int j = 0; j < 4; ++j)
            bf[j] = *(const short8v*)&Bs[(wc * 64 + j * 16 + lr) * 32 + lhi * 8];
        #pragma unroll
        for (int i = 0; i < 4; ++i)
            #pragma unroll
            for (int j = 0; j < 4; ++j)
                acc[i][j] = __builtin_amdgcn_mfma_f32_16x16x32_bf16(af[i], bf[j], acc[i][j], 0, 0, 0);
    }
    #pragma unroll
    for (int i = 0; i < 4; ++i) {
        int row = m0 + wr * 64 + i * 16 + lhi * 4;
        #pragma unroll
        for (int j = 0; j < 4; ++j) {
            int col = n0 + wc * 64 + j * 16 + lr;
            float bv = bias[col];
            #pragma unroll
            for (int r = 0; r < 4; ++r)
                C[(row + r) * N + col] = acc[i][j][r] + bv;
        }
    }
}

// ---------------- LSTM recurrence (both directions) ----------------
// Data-as-flag exchange: h stored as 64-bit {tag=t+1 | fp32 h} agent-scope
// atomic words; consumers poll the exact 8 words they need until the tag
// matches. No counter barrier, no vmcnt ack, no separate reload.
// Safety: double-buffer parity + exact tag; a wg can only overwrite slot
// h(t-1) after consuming h(t), which requires all peers stored h(t), which
// requires they consumed h(t-1). k_init zeroes tags each launch.
__global__ __launch_bounds__(256, 1)
void k_lstm(const float* __restrict__ xs_f, const float* __restrict__ xs_b,
            const float* __restrict__ whh_f, const float* __restrict__ whh_b,
            unsigned short* __restrict__ xout, unsigned long long* __restrict__ hbuf)
{
    const int tid = threadIdx.x;
    const int wid = blockIdx.x;
    const int grp = wid & 31;       // dir*16 + bs
    const int gs  = wid >> 5;       // 0..7
    const int dir = grp >> 4;
    const int bs  = grp & 15;
    const int j0 = gs * 32, b0 = bs * 8;
    const float* xs  = dir ? xs_b : xs_f;
    const float* whh = dir ? whh_b : whh_f;
    unsigned long long* hb = hbuf + (size_t)dir * (2 * 128 * 256);

    const int ri = tid & 31, kq = tid >> 5;
    float wreg[4][32];
    #pragma unroll
    for (int rr = 0; rr < 4; ++rr) {
        int r = 4 * ri + rr;
        int g = r >> 5, jj = r & 31;
        const float* wrow = whh + (g * 256 + j0 + jj) * 256 + kq * 32;
        #pragma unroll
        for (int kk = 0; kk < 32; ++kk) wreg[rr][kk] = wrow[kk];
    }
    const int jj_u = tid & 31, bb_u = tid >> 5;
    float c_reg = 0.f;

    __shared__ float Hs[8][260];
    __shared__ float ps[8][128][9];

    const float* xr0 = xs + ((b0 + bb_u) * 128 + (dir ? 127 : 0)) * 1024 + j0 + jj_u;
    float xi = xr0[0], xf = xr0[256], xg = xr0[512], xo = xr0[768];

    for (int t = 0; t < 128; ++t) {
        const int l = dir ? (127 - t) : t;
        const int n_u = (b0 + bb_u) * 128 + l;

        if (t > 0) {
            // poll-load h slice (8 rows x 256): tag must equal t
            const unsigned long long* hp =
                hb + (t & 1) * (128 * 256) + (b0 + (tid >> 5)) * 256 + (tid & 31) * 8;
            unsigned long long u[8];
            #pragma unroll
            for (int q = 0; q < 8; ++q)
                u[q] = __hip_atomic_load(hp + q, __ATOMIC_RELAXED,
                                         __HIP_MEMORY_SCOPE_AGENT);
            #pragma unroll
            for (int q = 0; q < 8; ++q) {
                while ((unsigned)(u[q] >> 32) != (unsigned)t)
                    u[q] = __hip_atomic_load(hp + q, __ATOMIC_RELAXED,
                                             __HIP_MEMORY_SCOPE_AGENT);
                union { unsigned u; float f; } cv; cv.u = (unsigned)u[q];
                Hs[tid >> 5][(tid & 31) * 8 + q] = cv.f;
            }
            __syncthreads();
            float accp[4][8];
            #pragma unroll
            for (int rr = 0; rr < 4; ++rr)
                #pragma unroll
                for (int bb = 0; bb < 8; ++bb) accp[rr][bb] = 0.f;
            #pragma unroll
            for (int k4 = 0; k4 < 8; ++k4) {
                #pragma unroll
                for (int bb = 0; bb < 8; ++bb) {
                    float4 h4 = *(const float4*)&Hs[bb][kq * 32 + k4 * 4];
                    #pragma unroll
                    for (int rr = 0; rr < 4; ++rr) {
                        accp[rr][bb] += wreg[rr][k4*4+0] * h4.x
                                      + wreg[rr][k4*4+1] * h4.y
                                      + wreg[rr][k4*4+2] * h4.z
                                      + wreg[rr][k4*4+3] * h4.w;
                    }
                }
            }
            #pragma unroll
            for (int rr = 0; rr < 4; ++rr) {
                int r = 4 * ri + rr;
                #pragma unroll
                for (int bb = 0; bb < 8; ++bb) ps[kq][r][bb] = accp[rr][bb];
            }
        }
        __syncthreads();

        float gi = xi, gf = xf, gg = xg, go = xo;
        if (t > 0) {
            #pragma unroll
            for (int q = 0; q < 8; ++q) {
                gi += ps[q][     jj_u][bb_u];
                gf += ps[q][32 + jj_u][bb_u];
                gg += ps[q][64 + jj_u][bb_u];
                go += ps[q][96 + jj_u][bb_u];
            }
        }
        gi = 1.f / (1.f + expf(-gi));
        gf = 1.f / (1.f + expf(-gf));
        gg = tanhf(gg);
        go = 1.f / (1.f + expf(-go));
        c_reg = gf * c_reg + gi * gg;
        float h = go * tanhf(c_reg);

        xout[n_u * 512 + dir * 256 + j0 + jj_u] = f2bf(h);
        if (t < 127) {
            union { float f; unsigned u; } hv; hv.f = h;
            unsigned long long pu = ((unsigned long long)(unsigned)(t + 1) << 32) | hv.u;
            __hip_atomic_store(hb + ((t + 1) & 1) * (128 * 256)
                                  + (b0 + bb_u) * 256 + j0 + jj_u,
                               pu, __ATOMIC_RELAXED, __HIP_MEMORY_SCOPE_AGENT);
            // prefetch x(t+1)
            const int l2 = dir ? (126 - t) : (t + 1);
            const float* xr2 = xs + ((b0 + bb_u) * 128 + l2) * 1024 + j0 + jj_u;
            xi = xr2[0]; xf = xr2[256]; xg = xr2[512]; xo = xr2[768];
        }
    }
}

// ---------------- CSR build ----------------
__global__ void k_hist(const int* __restrict__ ei, int* __restrict__ deg) {
    int e = blockIdx.x * 256 + threadIdx.x;
    if (e >= EE) return;
    atomicAdd(&deg[ei[EE + e]], 1);
}

__global__ void k_scan(const int* __restrict__ deg, int* __restrict__ indptr) {
    __shared__ int sm[256];
    int tid = threadIdx.x;
    int b0 = tid * 64;
    int s = 0;
    for (int i = 0; i < 64; ++i) s += deg[b0 + i];
    sm[tid] = s;
    __syncthreads();
    for (int off = 1; off < 256; off <<= 1) {
        int v = (tid >= off) ? sm[tid - off] : 0;
        __syncthreads();
        sm[tid] += v;
        __syncthreads();
    }
    int run = sm[tid] - s;   // exclusive prefix
    for (int i = 0; i < 64; ++i) { indptr[b0 + i] = run; run += deg[b0 + i]; }
    if (tid == 255) indptr[NN] = run;
}

__global__ void k_scatter(const int* __restrict__ ei, const int* __restrict__ indptr,
                          int* __restrict__ fill, int* __restrict__ cols) {
    int e = blockIdx.x * 256 + threadIdx.x;
    if (e >= EE) return;
    int d = ei[EE + e];
    int slot = atomicAdd(&fill[d], 1);
    cols[indptr[d] + slot] = ei[e];
}

// ---------------- SAGE neighbor mean + concat -> bf16 ----------------
// fp32-input variant (layers 2,3)
__global__ __launch_bounds__(256)
void k_gather(const float* __restrict__ x, const int* __restrict__ indptr,
              const int* __restrict__ cols, unsigned short* __restrict__ catb)
{
    int gw = (blockIdx.x * 256 + threadIdx.x) >> 6;
    int lane = threadIdx.x & 63;
    if (gw >= NN) return;
    int s = indptr[gw], e = indptr[gw + 1];
    float a0=0,a1=0,a2=0,a3=0,a4=0,a5=0,a6=0,a7=0;
    for (int p = s; p < e; ++p) {
        const float4* xp = (const float4*)(x + cols[p] * 512 + lane * 8);
        float4 v0 = xp[0], v1 = xp[1];
        a0 += v0.x; a1 += v0.y; a2 += v0.z; a3 += v0.w;
        a4 += v1.x; a5 += v1.y; a6 += v1.z; a7 += v1.w;
    }
    float sc = 1.f / (float)((e - s) > 1 ? (e - s) : 1);
    unsigned short* cp = catb + gw * 1024 + lane * 8;
    unsigned short o[8];
    o[0]=f2bf(a0*sc); o[1]=f2bf(a1*sc); o[2]=f2bf(a2*sc); o[3]=f2bf(a3*sc);
    o[4]=f2bf(a4*sc); o[5]=f2bf(a5*sc); o[6]=f2bf(a6*sc); o[7]=f2bf(a7*sc);
    *(short8v*)cp = *(short8v*)o;
    const float4* xp = (const float4*)(x + gw * 512 + lane * 8);
    float4 v0 = xp[0], v1 = xp[1];
    o[0]=f2bf(v0.x); o[1]=f2bf(v0.y); o[2]=f2bf(v0.z); o[3]=f2bf(v0.w);
    o[4]=f2bf(v1.x); o[5]=f2bf(v1.y); o[6]=f2bf(v1.z); o[7]=f2bf(v1.w);
    *(short8v*)(cp + 512) = *(short8v*)o;
}

// bf16-input variant (layer 1, reads x0b)
__global__ __launch_bounds__(256)
void k_gather_bf(const unsigned short* __restrict__ x, const int* __restrict__ indptr,
                 const int* __restrict__ cols, unsigned short* __restrict__ catb)
{
    int gw = (blockIdx.x * 256 + threadIdx.x) >> 6;
    int lane = threadIdx.x & 63;
    if (gw >= NN) return;
    int s = indptr[gw], e = indptr[gw + 1];
    float a[8] = {};
    for (int p = s; p < e; ++p) {
        short8v v = *(const short8v*)(x + cols[p] * 512 + lane * 8);
        #pragma unroll
        for (int q = 0; q < 8; ++q) a[q] += bf2f((unsigned short)v[q]);
    }
    float sc = 1.f / (float)((e - s) > 1 ? (e - s) : 1);
    unsigned short* cp = catb + gw * 1024 + lane * 8;
    unsigned short o[8];
    #pragma unroll
    for (int q = 0; q < 8; ++q) o[q] = f2bf(a[q] * sc);
    *(short8v*)cp = *(short8v*)o;
    *(short8v*)(cp + 512) = *(const short8v*)(x + gw * 512 + lane * 8);
}

// ---------------- row L2-normalize + relu (in place) ----------------
__global__ __launch_bounds__(256)
void k_norm_relu(float* __restrict__ y)
{
    int gw = (blockIdx.x * 256 + threadIdx.x) >> 6;
    int lane = threadIdx.x & 63;
    if (gw >= NN) return;
    float* row = y + gw * 512 + lane * 8;
    float4 v0 = *(const float4*)row;
    float4 v1 = *(const float4*)(row + 4);
    float ss = v0.x*v0.x + v0.y*v0.y + v0.z*v0.z + v0.w*v0.w
             + v1.x*v1.x + v1.y*v1.y + v1.z*v1.z + v1.w*v1.w;
    #pragma unroll
    for (int off = 32; off >= 1; off >>= 1) ss += __shfl_xor(ss, off);
    float sc = 1.f / fmaxf(sqrtf(ss), 1e-12f);
    float4 o0, o1;
    o0.x = fmaxf(v0.x*sc, 0.f); o0.y = fmaxf(v0.y*sc, 0.f);
    o0.z = fmaxf(v0.z*sc, 0.f); o0.w = fmaxf(v0.w*sc, 0.f);
    o1.x = fmaxf(v1.x*sc, 0.f); o1.y = fmaxf(v1.y*sc, 0.f);
    o1.z = fmaxf(v1.z*sc, 0.f); o1.w = fmaxf(v1.w*sc, 0.f);
    *(float4*)row = o0;
    *(float4*)(row + 4) = o1;
}

// ---------------- mean-pool per graph + linear head ----------------
__global__ __launch_bounds__(256)
void k_pool(const float* __restrict__ x, const float* __restrict__ Wlin,
            const float* __restrict__ blin, float* __restrict__ out)
{
    int g = blockIdx.x;
    int tid = threadIdx.x;
    const float* base = x + g * 128 * 512;
    float a0 = 0.f, a1 = 0.f;
    for (int r = 0; r < 128; ++r) {
        a0 += base[r * 512 + 2*tid];
        a1 += base[r * 512 + 2*tid + 1];
    }
    __shared__ float pooled[512];
    pooled[2*tid]     = a0 * (1.f / 128.f);
    pooled[2*tid + 1] = a1 * (1.f / 128.f);
    __syncthreads();
    if (tid < 64) {
        float p0 = 0.f, p1 = 0.f;
        for (int k = tid; k < 512; k += 64) {
            float pv = pooled[k];
            p0 += pv * Wlin[2*k];
            p1 += pv * Wlin[2*k + 1];
        }
        #pragma unroll
        for (int off = 32; off >= 1; off >>= 1) {
            p0 += __shfl_xor(p0, off);
            p1 += __shfl_xor(p1, off);
        }
        if (tid == 0) {
            out[2*g]     = p0 + blin[0];
            out[2*g + 1] = p1 + blin[1];
        }
    }
}

extern "C" void kernel_launch(void* const* d_in, const int* in_sizes, int n_in,
                              void* d_out, int out_size, void* d_ws, size_t ws_size,
                              hipStream_t stream)
{
    (void)in_sizes; (void)n_in; (void)out_size; (void)ws_size;
    const int*   word_seq = (const int*)  d_in[0];
    const int*   ei       = (const int*)  d_in[1];
    const float* tab      = (const float*)d_in[3];
    const float* wih_f    = (const float*)d_in[4];
    const float* whh_f    = (const float*)d_in[5];
    const float* b_f      = (const float*)d_in[6];
    const float* wih_b    = (const float*)d_in[7];
    const float* whh_b    = (const float*)d_in[8];
    const float* b_b      = (const float*)d_in[9];
    const float* Wl1      = (const float*)d_in[10];
    const float* Wr1      = (const float*)d_in[11];
    const float* b1       = (const float*)d_in[12];
    const float* Wl2      = (const float*)d_in[13];
    const float* Wr2      = (const float*)d_in[14];
    const float* b2       = (const float*)d_in[15];
    const float* Wl3      = (const float*)d_in[16];
    const float* Wr3      = (const float*)d_in[17];
    const float* b3       = (const float*)d_in[18];
    const float* Wlin     = (const float*)d_in[19];
    const float* blin     = (const float*)d_in[20];
    float* out = (float*)d_out;

    char* w = (char*)d_ws;
    int*   deg    = (int*)  (w);                    //     65,536
    int*   indptr = (int*)  (w + 65536);            //     66,048
    int*   fill   = (int*)  (w + 131584);           //     65,536
    int*   cols   = (int*)  (w + 197120);           //  1,048,576
    unsigned long long* hbuf = (unsigned long long*)(w + 1245696);  // 2,097,152
    unsigned short* wt_f = (unsigned short*)(w + 3342848);   // 655,360
    unsigned short* wt_b = (unsigned short*)(w + 3998208);   // 655,360
    unsigned short* wc1  = (unsigned short*)(w + 4653568);   // 1,048,576
    unsigned short* wc2  = (unsigned short*)(w + 5702144);   // 1,048,576
    unsigned short* wc3  = (unsigned short*)(w + 6750720);   // 1,048,576
    unsigned short* xeb  = (unsigned short*)(w + 7799296);   // 10,485,760
    float* xs_f   = (float*)(w + 18285056);         // 67,108,864
    float* xs_b   = (float*)(w + 85393920);         // 67,108,864
    unsigned short* x0b = (unsigned short*)(w + 152502784);  // 16,777,216 (end ~169.3 MB)
    unsigned short* catb = (unsigned short*)(w + 18285056);  // reuse xs_f[0:32M]
    float* x1     = (float*)(w + 51839488);         // reuse xs_f[32M:64M]
    float* x2     = (float*)(w + 85393920);         // reuse xs_b[0:32M]

    // conversions + embedding (bf16)
    k_embed_bf<<<20480, 256, 0, stream>>>(word_seq, tab, xeb);
    k_cvt_wih<<<1280, 256, 0, stream>>>(wih_f, wt_f);
    k_cvt_wih<<<1280, 256, 0, stream>>>(wih_b, wt_b);
    k_cvt_wcat<<<2048, 256, 0, stream>>>(Wl1, Wr1, wc1);
    k_cvt_wcat<<<2048, 256, 0, stream>>>(Wl2, Wr2, wc2);
    k_cvt_wcat<<<2048, 256, 0, stream>>>(Wl3, Wr3, wc3);

    // CSR build + hbuf tag clear
    k_init<<<1024, 256, 0, stream>>>(hbuf, deg, fill);
    k_hist<<<1024, 256, 0, stream>>>(ei, deg);
    k_scan<<<1, 256, 0, stream>>>(deg, indptr);
    k_scatter<<<1024, 256, 0, stream>>>(ei, indptr, fill, cols);

    // LSTM input projections (bf16 MFMA): xs = xeb @ wt^T + b
    k_mgemm<<<dim3(128, 8), 256, 0, stream>>>(xeb, wt_f, b_f, xs_f, 1024, 320);
    k_mgemm<<<dim3(128, 8), 256, 0, stream>>>(xeb, wt_b, b_b, xs_b, 1024, 320);

    // bidirectional LSTM scan -> x0b = [hf | hb] (bf16)
    k_lstm<<<256, 256, 0, stream>>>(xs_f, xs_b, whh_f, whh_b, x0b, hbuf);

    // SAGE layer 1
    k_gather_bf<<<4096, 256, 0, stream>>>(x0b, indptr, cols, catb);
    k_mgemm<<<dim3(128, 4), 256, 0, stream>>>(catb, wc1, b1, x1, 512, 1024);
    k_norm_relu<<<4096, 256, 0, stream>>>(x1);
    // SAGE layer 2
    k_gather<<<4096, 256, 0, stream>>>(x1, indptr, cols, catb);
    k_mgemm<<<dim3(128, 4), 256, 0, stream>>>(catb, wc2, b2, x2, 512, 1024);
    k_norm_relu<<<4096, 256, 0, stream>>>(x2);
    // SAGE layer 3
    k_gather<<<4096, 256, 0, stream>>>(x2, indptr, cols, catb);
    k_mgemm<<<dim3(128, 4), 256, 0, stream>>>(catb, wc3, b3, x1, 512, 1024);
    k_norm_relu<<<4096, 256, 0, stream>>>(x1);

    // mean pool per graph + linear head
    k_pool<<<128, 256, 0, stream>>>(x1, Wlin, blin, out);
}

// Round 5
// 800.373 us; speedup vs baseline: 8.1279x; 1.6799x over previous
//
#include <hip/hip_runtime.h>
#include <math.h>

#define NN   16384
#define EE   262144

typedef __attribute__((ext_vector_type(8))) short  short8v;   // 8 bf16 = 4 VGPR
typedef __attribute__((ext_vector_type(4))) float  f32x4;

__device__ inline unsigned short f2bf(float f) {
    union { float f; unsigned u; } v; v.f = f;
    unsigned r = v.u + 0x7fff + ((v.u >> 16) & 1);   // RNE
    return (unsigned short)(r >> 16);
}
__device__ inline float bf2f(unsigned short b) {
    unsigned u = ((unsigned)b) << 16;
    union { unsigned u; float f; } v; v.u = u; return v.f;
}
__device__ inline float sigm_f(float x) { return 1.f / (1.f + __expf(-x)); }
__device__ inline float tanh_f(float x) {
    x = fminf(15.f, fmaxf(-15.f, x));
    float e = __expf(2.f * x);
    return (e - 1.f) / (e + 1.f);
}
// gate-column permutation: n' = w'*64 + g*16 + jj  <->  orig = g*256 + w'*16 + jj
__device__ inline int gate_orig(int np) {
    int wp = np >> 6, g = (np >> 4) & 3, jj = np & 15;
    return g * 256 + wp * 16 + jj;
}

// ---------------- init (zero hx tags / deg / fill) ----------------
__global__ void k_init(unsigned long long* __restrict__ hx, int* __restrict__ deg,
                       int* __restrict__ fill) {
    int i = blockIdx.x * 256 + threadIdx.x;
    if (i < 65536) hx[i] = 0ull;            // tag=0 matches no wanted tag (>=1)
    if (i < NN) { deg[i] = 0; fill[i] = 0; }
}

// ---------------- embedding gather -> bf16, K padded 300->320 ----------------
__global__ void k_embed_bf(const int* __restrict__ wseq, const float* __restrict__ tab,
                           unsigned short* __restrict__ xeb) {
    int i = blockIdx.x * 256 + threadIdx.x;
    if (i >= NN * 320) return;
    int row = i / 320, k = i - row * 320;
    float f = (k < 300) ? tab[wseq[row] * 300 + k] : 0.f;
    xeb[i] = f2bf(f);
}

// ---------------- weight conversions ----------------
// wih (1024,300) fp32 -> wt (1024,320) bf16, rows permuted to gate-interleaved order
__global__ void k_cvt_wih(const float* __restrict__ wih, unsigned short* __restrict__ wt) {
    int i = blockIdx.x * 256 + threadIdx.x;
    if (i >= 1024 * 320) return;
    int np = i / 320, k = i - np * 320;
    wt[i] = f2bf(k < 300 ? wih[gate_orig(np) * 300 + k] : 0.f);
}
// whh (1024,256) fp32 -> bf16, rows permuted
__global__ void k_cvt_whh(const float* __restrict__ whh, unsigned short* __restrict__ wp) {
    int i = blockIdx.x * 256 + threadIdx.x;
    if (i >= 1024 * 256) return;
    int np = i >> 8, k = i & 255;
    wp[i] = f2bf(whh[gate_orig(np) * 256 + k]);
}
// bias permute
__global__ void k_permb(const float* __restrict__ b, float* __restrict__ pb) {
    int i = blockIdx.x * 256 + threadIdx.x;
    if (i < 1024) pb[i] = b[gate_orig(i)];
}
// Wl,Wr (512,512) fp32 -> wc (512,1024) bf16: wc[n][k] = k<512 ? Wl[k][n] : Wr[k-512][n]
__global__ void k_cvt_wcat(const float* __restrict__ Wl, const float* __restrict__ Wr,
                           unsigned short* __restrict__ wc) {
    int i = blockIdx.x * 256 + threadIdx.x;
    if (i >= 512 * 1024) return;
    int n = i >> 10, k = i & 1023;
    float f = (k < 512) ? Wl[k * 512 + n] : Wr[(k - 512) * 512 + n];
    wc[i] = f2bf(f);
}

// ---------------- bf16 MFMA GEMM: C[M][N] = A[M][Ka] * Bt[N][Ka]^T + bias ----------------
__global__ __launch_bounds__(256)
void k_mgemm(const unsigned short* __restrict__ A, const unsigned short* __restrict__ Bt,
             const float* __restrict__ bias, float* __restrict__ C, int N, int Ka)
{
    __shared__ unsigned short As[128 * 32];
    __shared__ unsigned short Bs[128 * 32];
    const int tid = threadIdx.x;
    const int m0 = blockIdx.x << 7, n0 = blockIdx.y << 7;
    const int w = tid >> 6, lane = tid & 63;
    const int wr = w >> 1, wc = w & 1;
    const int lr = lane & 15, lhi = lane >> 4;
    const int r0 = tid >> 2, kc0 = (tid & 3) * 8;

    f32x4 acc[4][4] = {};

    for (int k0 = 0; k0 < Ka; k0 += 32) {
        short8v a0 = *(const short8v*)(A + (m0 + r0) * Ka + k0 + kc0);
        short8v a1 = *(const short8v*)(A + (m0 + 64 + r0) * Ka + k0 + kc0);
        short8v b0 = *(const short8v*)(Bt + (n0 + r0) * Ka + k0 + kc0);
        short8v b1 = *(const short8v*)(Bt + (n0 + 64 + r0) * Ka + k0 + kc0);
        __syncthreads();
        *(short8v*)&As[r0 * 32 + kc0]        = a0;
        *(short8v*)&As[(64 + r0) * 32 + kc0] = a1;
        *(short8v*)&Bs[r0 * 32 + kc0]        = b0;
        *(short8v*)&Bs[(64 + r0) * 32 + kc0] = b1;
        __syncthreads();
        short8v af[4], bf[4];
        #pragma unroll
        for (int i = 0; i < 4; ++i)
            af[i] = *(const short8v*)&As[(wr * 64 + i * 16 + lr) * 32 + lhi * 8];
        #pragma unroll
        for (int j = 0; j < 4; ++j)
            bf[j] = *(const short8v*)&Bs[(wc * 64 + j * 16 + lr) * 32 + lhi * 8];
        #pragma unroll
        for (int i = 0; i < 4; ++i)
            #pragma unroll
            for (int j = 0; j < 4; ++j)
                acc[i][j] = __builtin_amdgcn_mfma_f32_16x16x32_bf16(af[i], bf[j], acc[i][j], 0, 0, 0);
    }
    #pragma unroll
    for (int i = 0; i < 4; ++i) {
        int row = m0 + wr * 64 + i * 16 + lhi * 4;
        #pragma unroll
        for (int j = 0; j < 4; ++j) {
            int col = n0 + wc * 64 + j * 16 + lr;
            float bv = bias[col];
            #pragma unroll
            for (int r = 0; r < 4; ++r)
                C[(row + r) * N + col] = acc[i][j][r] + bv;
        }
    }
}

// ---------------- LSTM recurrence: MFMA, whh in VGPRs ----------------
// wg = 512 thr (8 waves) per (dir, 16-batch-rows, hidden-half H); grid 32.
// Wave owns 64 permuted gate-cols (= 16 hidden j x 4 gates); whh B-frags
// preloaded to 128 VGPRs. h(t) lives in LDS A-tile [2][16][256] bf16,
// XOR-swizzled (byte ^ (row&7)<<4). Peer hidden-half exchanged per step via
// 64-bit {tag|2xbf16} data-as-flag words (1024 words = 4 KB per half).
__global__ __launch_bounds__(512, 2)
void k_lstm(const float* __restrict__ xs_f, const float* __restrict__ xs_b,
            const unsigned short* __restrict__ whhp_f, const unsigned short* __restrict__ whhp_b,
            unsigned short* __restrict__ xout, unsigned long long* __restrict__ hx)
{
    const int tid  = threadIdx.x;
    const int wv   = tid >> 6, lane = tid & 63;
    const int lr   = lane & 15, lh = lane >> 4;
    const int wgid = blockIdx.x;            // dir*16 + bs*2 + H
    const int dir  = wgid >> 4;
    const int bs   = (wgid >> 1) & 7;
    const int H    = wgid & 1;
    const int b0   = bs * 16;
    const float* xs = dir ? xs_b : xs_f;
    const unsigned short* whhp = dir ? whhp_b : whhp_f;

    // B-frag preload: col n' = H*512 + wv*64 + g*16 + lr, k = ks*32 + lh*8 + e
    short8v wf[4][8];
    #pragma unroll
    for (int g = 0; g < 4; ++g)
        #pragma unroll
        for (int ks = 0; ks < 8; ++ks)
            wf[g][ks] = *(const short8v*)(whhp
                + (size_t)(H * 512 + wv * 64 + g * 16 + lr) * 256 + ks * 32 + lh * 8);

    __shared__ unsigned short At[2][16 * 256];   // [parity][row][k] bf16, swizzled

    unsigned long long* hx_own =
        hx + (size_t)(((dir * 8 + bs) * 2 + H) * 2) * 1024;
    const unsigned long long* hx_peer =
        hx + (size_t)(((dir * 8 + bs) * 2 + (1 - H)) * 2) * 1024;

    const int jmine = H * 128 + wv * 16 + lr;    // my hidden index
    const int rowb  = 4 * lh;                    // my 4 batch rows (within slice)
    // unpack role: thread t -> peer j' = t>>2, rows 4*(t&3)..+3, words 2t,2t+1
    const int up_j    = (1 - H) * 128 + (tid >> 2);
    const int up_rowb = 4 * (tid & 3);
    const int xcol    = H * 512 + wv * 64 + lr;  // xs col base (add g*16)

    float c[4] = {0.f, 0.f, 0.f, 0.f};
    float xv[4][4];                              // [gate][row]
    {
        const int l0 = dir ? 127 : 0;
        #pragma unroll
        for (int r = 0; r < 4; ++r) {
            const float* xp = xs + ((size_t)(b0 + rowb + r) * 128 + l0) * 1024 + xcol;
            #pragma unroll
            for (int g = 0; g < 4; ++g) xv[g][r] = xp[g * 16];
        }
    }

    for (int t = 0; t < 128; ++t) {
        const int l = dir ? (127 - t) : t;
        f32x4 acc[4] = {};
        if (t > 0) {
            const char* Ab = (const char*)&At[(t - 1) & 1][0];
            #pragma unroll
            for (int ks = 0; ks < 8; ++ks) {
                int off = (lr * 512 + ks * 64 + lh * 16) ^ ((lr & 7) << 4);
                short8v a = *(const short8v*)(Ab + off);
                #pragma unroll
                for (int g = 0; g < 4; ++g)
                    acc[g] = __builtin_amdgcn_mfma_f32_16x16x32_bf16(a, wf[g][ks], acc[g], 0, 0, 0);
            }
        }
        unsigned short hb[4];
        #pragma unroll
        for (int r = 0; r < 4; ++r) {
            float gi = sigm_f(acc[0][r] + xv[0][r]);
            float gf = sigm_f(acc[1][r] + xv[1][r]);
            float gg = tanh_f(acc[2][r] + xv[2][r]);
            float go = sigm_f(acc[3][r] + xv[3][r]);
            c[r] = gf * c[r] + gi * gg;
            float h = go * tanh_f(c[r]);
            hb[r] = f2bf(h);
            xout[((size_t)(b0 + rowb + r) * 128 + l) * 512 + dir * 256 + jmine] = hb[r];
        }
        if (t < 127) {
            const int p = t & 1;
            char* Aw = (char*)&At[p][0];
            #pragma unroll
            for (int r = 0; r < 4; ++r) {
                int row = rowb + r;
                int off = (row * 512 + 2 * jmine) ^ ((row & 7) << 4);
                *(unsigned short*)(Aw + off) = hb[r];
            }
            const unsigned tg = (unsigned)(t + 1);
            unsigned long long w0 = ((unsigned long long)tg << 32)
                                  | ((unsigned)hb[0] | ((unsigned)hb[1] << 16));
            unsigned long long w1 = ((unsigned long long)tg << 32)
                                  | ((unsigned)hb[2] | ((unsigned)hb[3] << 16));
            const int Wb = (wv * 16 + lr) * 8 + 2 * lh;
            __hip_atomic_store(hx_own + (size_t)p * 1024 + Wb,     w0,
                               __ATOMIC_RELAXED, __HIP_MEMORY_SCOPE_AGENT);
            __hip_atomic_store(hx_own + (size_t)p * 1024 + Wb + 1, w1,
                               __ATOMIC_RELAXED, __HIP_MEMORY_SCOPE_AGENT);
            // prefetch xs(t+1) (in flight across poll + barrier)
            const int l2 = dir ? (126 - t) : (t + 1);
            #pragma unroll
            for (int r = 0; r < 4; ++r) {
                const float* xp = xs + ((size_t)(b0 + rowb + r) * 128 + l2) * 1024 + xcol;
                #pragma unroll
                for (int g = 0; g < 4; ++g) xv[g][r] = xp[g * 16];
            }
            // poll peer half, unpack into LDS
            const unsigned long long* pp = hx_peer + (size_t)p * 1024 + 2 * tid;
            unsigned long long u0 = __hip_atomic_load(pp,     __ATOMIC_RELAXED, __HIP_MEMORY_SCOPE_AGENT);
            unsigned long long u1 = __hip_atomic_load(pp + 1, __ATOMIC_RELAXED, __HIP_MEMORY_SCOPE_AGENT);
            while ((unsigned)(u0 >> 32) != tg)
                u0 = __hip_atomic_load(pp,     __ATOMIC_RELAXED, __HIP_MEMORY_SCOPE_AGENT);
            while ((unsigned)(u1 >> 32) != tg)
                u1 = __hip_atomic_load(pp + 1, __ATOMIC_RELAXED, __HIP_MEMORY_SCOPE_AGENT);
            {
                int r0_ = up_rowb, r1_ = up_rowb + 1, r2_ = up_rowb + 2, r3_ = up_rowb + 3;
                *(unsigned short*)(Aw + ((r0_ * 512 + 2 * up_j) ^ ((r0_ & 7) << 4))) =
                    (unsigned short)(u0 & 0xffff);
                *(unsigned short*)(Aw + ((r1_ * 512 + 2 * up_j) ^ ((r1_ & 7) << 4))) =
                    (unsigned short)((u0 >> 16) & 0xffff);
                *(unsigned short*)(Aw + ((r2_ * 512 + 2 * up_j) ^ ((r2_ & 7) << 4))) =
                    (unsigned short)(u1 & 0xffff);
                *(unsigned short*)(Aw + ((r3_ * 512 + 2 * up_j) ^ ((r3_ & 7) << 4))) =
                    (unsigned short)((u1 >> 16) & 0xffff);
            }
            __syncthreads();
        }
    }
}

// ---------------- CSR build ----------------
__global__ void k_hist(const int* __restrict__ ei, int* __restrict__ deg) {
    int e = blockIdx.x * 256 + threadIdx.x;
    if (e >= EE) return;
    atomicAdd(&deg[ei[EE + e]], 1);
}

__global__ void k_scan(const int* __restrict__ deg, int* __restrict__ indptr) {
    __shared__ int sm[256];
    int tid = threadIdx.x;
    int b0 = tid * 64;
    int s = 0;
    for (int i = 0; i < 64; ++i) s += deg[b0 + i];
    sm[tid] = s;
    __syncthreads();
    for (int off = 1; off < 256; off <<= 1) {
        int v = (tid >= off) ? sm[tid - off] : 0;
        __syncthreads();
        sm[tid] += v;
        __syncthreads();
    }
    int run = sm[tid] - s;   // exclusive prefix
    for (int i = 0; i < 64; ++i) { indptr[b0 + i] = run; run += deg[b0 + i]; }
    if (tid == 255) indptr[NN] = run;
}

__global__ void k_scatter(const int* __restrict__ ei, const int* __restrict__ indptr,
                          int* __restrict__ fill, int* __restrict__ cols) {
    int e = blockIdx.x * 256 + threadIdx.x;
    if (e >= EE) return;
    int d = ei[EE + e];
    int slot = atomicAdd(&fill[d], 1);
    cols[indptr[d] + slot] = ei[e];
}

// ---------------- SAGE neighbor mean + concat -> bf16 ----------------
__global__ __launch_bounds__(256)
void k_gather(const float* __restrict__ x, const int* __restrict__ indptr,
              const int* __restrict__ cols, unsigned short* __restrict__ catb)
{
    int gw = (blockIdx.x * 256 + threadIdx.x) >> 6;
    int lane = threadIdx.x & 63;
    if (gw >= NN) return;
    int s = indptr[gw], e = indptr[gw + 1];
    float a0=0,a1=0,a2=0,a3=0,a4=0,a5=0,a6=0,a7=0;
    for (int p = s; p < e; ++p) {
        const float4* xp = (const float4*)(x + cols[p] * 512 + lane * 8);
        float4 v0 = xp[0], v1 = xp[1];
        a0 += v0.x; a1 += v0.y; a2 += v0.z; a3 += v0.w;
        a4 += v1.x; a5 += v1.y; a6 += v1.z; a7 += v1.w;
    }
    float sc = 1.f / (float)((e - s) > 1 ? (e - s) : 1);
    unsigned short* cp = catb + gw * 1024 + lane * 8;
    unsigned short o[8];
    o[0]=f2bf(a0*sc); o[1]=f2bf(a1*sc); o[2]=f2bf(a2*sc); o[3]=f2bf(a3*sc);
    o[4]=f2bf(a4*sc); o[5]=f2bf(a5*sc); o[6]=f2bf(a6*sc); o[7]=f2bf(a7*sc);
    *(short8v*)cp = *(short8v*)o;
    const float4* xp = (const float4*)(x + gw * 512 + lane * 8);
    float4 v0 = xp[0], v1 = xp[1];
    o[0]=f2bf(v0.x); o[1]=f2bf(v0.y); o[2]=f2bf(v0.z); o[3]=f2bf(v0.w);
    o[4]=f2bf(v1.x); o[5]=f2bf(v1.y); o[6]=f2bf(v1.z); o[7]=f2bf(v1.w);
    *(short8v*)(cp + 512) = *(short8v*)o;
}

// bf16-input variant (layer 1, reads x0b)
__global__ __launch_bounds__(256)
void k_gather_bf(const unsigned short* __restrict__ x, const int* __restrict__ indptr,
                 const int* __restrict__ cols, unsigned short* __restrict__ catb)
{
    int gw = (blockIdx.x * 256 + threadIdx.x) >> 6;
    int lane = threadIdx.x & 63;
    if (gw >= NN) return;
    int s = indptr[gw], e = indptr[gw + 1];
    float a[8] = {};
    for (int p = s; p < e; ++p) {
        short8v v = *(const short8v*)(x + cols[p] * 512 + lane * 8);
        #pragma unroll
        for (int q = 0; q < 8; ++q) a[q] += bf2f((unsigned short)v[q]);
    }
    float sc = 1.f / (float)((e - s) > 1 ? (e - s) : 1);
    unsigned short* cp = catb + gw * 1024 + lane * 8;
    unsigned short o[8];
    #pragma unroll
    for (int q = 0; q < 8; ++q) o[q] = f2bf(a[q] * sc);
    *(short8v*)cp = *(short8v*)o;
    *(short8v*)(cp + 512) = *(const short8v*)(x + gw * 512 + lane * 8);
}

// ---------------- row L2-normalize + relu (in place) ----------------
__global__ __launch_bounds__(256)
void k_norm_relu(float* __restrict__ y)
{
    int gw = (blockIdx.x * 256 + threadIdx.x) >> 6;
    int lane = threadIdx.x & 63;
    if (gw >= NN) return;
    float* row = y + gw * 512 + lane * 8;
    float4 v0 = *(const float4*)row;
    float4 v1 = *(const float4*)(row + 4);
    float ss = v0.x*v0.x + v0.y*v0.y + v0.z*v0.z + v0.w*v0.w
             + v1.x*v1.x + v1.y*v1.y + v1.z*v1.z + v1.w*v1.w;
    #pragma unroll
    for (int off = 32; off >= 1; off >>= 1) ss += __shfl_xor(ss, off);
    float sc = 1.f / fmaxf(sqrtf(ss), 1e-12f);
    float4 o0, o1;
    o0.x = fmaxf(v0.x*sc, 0.f); o0.y = fmaxf(v0.y*sc, 0.f);
    o0.z = fmaxf(v0.z*sc, 0.f); o0.w = fmaxf(v0.w*sc, 0.f);
    o1.x = fmaxf(v1.x*sc, 0.f); o1.y = fmaxf(v1.y*sc, 0.f);
    o1.z = fmaxf(v1.z*sc, 0.f); o1.w = fmaxf(v1.w*sc, 0.f);
    *(float4*)row = o0;
    *(float4*)(row + 4) = o1;
}

// ---------------- mean-pool per graph + linear head ----------------
__global__ __launch_bounds__(256)
void k_pool(const float* __restrict__ x, const float* __restrict__ Wlin,
            const float* __restrict__ blin, float* __restrict__ out)
{
    int g = blockIdx.x;
    int tid = threadIdx.x;
    const float* base = x + g * 128 * 512;
    float a0 = 0.f, a1 = 0.f;
    for (int r = 0; r < 128; ++r) {
        a0 += base[r * 512 + 2*tid];
        a1 += base[r * 512 + 2*tid + 1];
    }
    __shared__ float pooled[512];
    pooled[2*tid]     = a0 * (1.f / 128.f);
    pooled[2*tid + 1] = a1 * (1.f / 128.f);
    __syncthreads();
    if (tid < 64) {
        float p0 = 0.f, p1 = 0.f;
        for (int k = tid; k < 512; k += 64) {
            float pv = pooled[k];
            p0 += pv * Wlin[2*k];
            p1 += pv * Wlin[2*k + 1];
        }
        #pragma unroll
        for (int off = 32; off >= 1; off >>= 1) {
            p0 += __shfl_xor(p0, off);
            p1 += __shfl_xor(p1, off);
        }
        if (tid == 0) {
            out[2*g]     = p0 + blin[0];
            out[2*g + 1] = p1 + blin[1];
        }
    }
}

extern "C" void kernel_launch(void* const* d_in, const int* in_sizes, int n_in,
                              void* d_out, int out_size, void* d_ws, size_t ws_size,
                              hipStream_t stream)
{
    (void)in_sizes; (void)n_in; (void)out_size; (void)ws_size;
    const int*   word_seq = (const int*)  d_in[0];
    const int*   ei       = (const int*)  d_in[1];
    const float* tab      = (const float*)d_in[3];
    const float* wih_f    = (const float*)d_in[4];
    const float* whh_f    = (const float*)d_in[5];
    const float* b_f      = (const float*)d_in[6];
    const float* wih_b    = (const float*)d_in[7];
    const float* whh_b    = (const float*)d_in[8];
    const float* b_b      = (const float*)d_in[9];
    const float* Wl1      = (const float*)d_in[10];
    const float* Wr1      = (const float*)d_in[11];
    const float* b1       = (const float*)d_in[12];
    const float* Wl2      = (const float*)d_in[13];
    const float* Wr2      = (const float*)d_in[14];
    const float* b2       = (const float*)d_in[15];
    const float* Wl3      = (const float*)d_in[16];
    const float* Wr3      = (const float*)d_in[17];
    const float* b3       = (const float*)d_in[18];
    const float* Wlin     = (const float*)d_in[19];
    const float* blin     = (const float*)d_in[20];
    float* out = (float*)d_out;

    char* w = (char*)d_ws;
    int*   deg    = (int*)  (w);                     //     65,536
    int*   indptr = (int*)  (w + 65536);             //     66,048
    int*   fill   = (int*)  (w + 131584);            //     65,536
    int*   cols   = (int*)  (w + 197120);            //  1,048,576
    unsigned long long* hx = (unsigned long long*)(w + 1245696);   // 524,288
    unsigned short* whhp_f = (unsigned short*)(w + 1769984);       // 524,288
    unsigned short* whhp_b = (unsigned short*)(w + 2294272);       // 524,288
    float* pb_f   = (float*)(w + 2818560);           //      4,096
    float* pb_b   = (float*)(w + 2822656);           //      4,096
    unsigned short* wt_f = (unsigned short*)(w + 2826752);   // 655,360
    unsigned short* wt_b = (unsigned short*)(w + 3482112);   // 655,360
    unsigned short* wc1  = (unsigned short*)(w + 4137472);   // 1,048,576
    unsigned short* wc2  = (unsigned short*)(w + 5186048);   // 1,048,576
    unsigned short* wc3  = (unsigned short*)(w + 6234624);   // 1,048,576
    unsigned short* xeb  = (unsigned short*)(w + 7283200);   // 10,485,760
    float* xs_f   = (float*)(w + 17768960);          // 67,108,864
    float* xs_b   = (float*)(w + 84877824);          // 67,108,864
    unsigned short* x0b = (unsigned short*)(w + 151986688);  // 16,777,216 (end ~161 MB)
    unsigned short* catb = (unsigned short*)(w + 17768960);  // reuse xs_f[0:33.5M]
    float* x1     = (float*)(w + 51323392);          // reuse xs_f[33.5M:67M]
    float* x2     = (float*)(w + 84877824);          // reuse xs_b[0:33.5M]

    // conversions + embedding (bf16)
    k_embed_bf<<<20480, 256, 0, stream>>>(word_seq, tab, xeb);
    k_cvt_wih<<<1280, 256, 0, stream>>>(wih_f, wt_f);
    k_cvt_wih<<<1280, 256, 0, stream>>>(wih_b, wt_b);
    k_cvt_whh<<<1024, 256, 0, stream>>>(whh_f, whhp_f);
    k_cvt_whh<<<1024, 256, 0, stream>>>(whh_b, whhp_b);
    k_permb<<<4, 256, 0, stream>>>(b_f, pb_f);
    k_permb<<<4, 256, 0, stream>>>(b_b, pb_b);
    k_cvt_wcat<<<2048, 256, 0, stream>>>(Wl1, Wr1, wc1);
    k_cvt_wcat<<<2048, 256, 0, stream>>>(Wl2, Wr2, wc2);
    k_cvt_wcat<<<2048, 256, 0, stream>>>(Wl3, Wr3, wc3);

    // CSR build + hx tag clear
    k_init<<<256, 256, 0, stream>>>(hx, deg, fill);
    k_hist<<<1024, 256, 0, stream>>>(ei, deg);
    k_scan<<<1, 256, 0, stream>>>(deg, indptr);
    k_scatter<<<1024, 256, 0, stream>>>(ei, indptr, fill, cols);

    // LSTM input projections (bf16 MFMA): xs = xeb @ wt^T + pb (permuted cols)
    k_mgemm<<<dim3(128, 8), 256, 0, stream>>>(xeb, wt_f, pb_f, xs_f, 1024, 320);
    k_mgemm<<<dim3(128, 8), 256, 0, stream>>>(xeb, wt_b, pb_b, xs_b, 1024, 320);

    // bidirectional LSTM scan -> x0b = [hf | hb] (bf16)
    k_lstm<<<32, 512, 0, stream>>>(xs_f, xs_b, whhp_f, whhp_b, x0b, hx);

    // SAGE layer 1
    k_gather_bf<<<4096, 256, 0, stream>>>(x0b, indptr, cols, catb);
    k_mgemm<<<dim3(128, 4), 256, 0, stream>>>(catb, wc1, b1, x1, 512, 1024);
    k_norm_relu<<<4096, 256, 0, stream>>>(x1);
    // SAGE layer 2
    k_gather<<<4096, 256, 0, stream>>>(x1, indptr, cols, catb);
    k_mgemm<<<dim3(128, 4), 256, 0, stream>>>(catb, wc2, b2, x2, 512, 1024);
    k_norm_relu<<<4096, 256, 0, stream>>>(x2);
    // SAGE layer 3
    k_gather<<<4096, 256, 0, stream>>>(x2, indptr, cols, catb);
    k_mgemm<<<dim3(128, 4), 256, 0, stream>>>(catb, wc3, b3, x1, 512, 1024);
    k_norm_relu<<<4096, 256, 0, stream>>>(x1);

    // mean pool per graph + linear head
    k_pool<<<128, 256, 0, stream>>>(x1, Wlin, blin, out);
}